// Round 14
// baseline (1863.362 us; speedup 1.0000x reference)
//
#include <hip/hip_runtime.h>
#include <math.h>

#define NP 15360
#define NPQ 15488
#define NTOK 15130
#define HG 123

typedef __attribute__((ext_vector_type(8))) short s8b;
typedef __attribute__((ext_vector_type(4))) float f4;

__device__ inline float bf2f(ushort u) { return __uint_as_float(((unsigned)u) << 16); }
__device__ inline ushort f2bf(float f) {
    unsigned u = __float_as_uint(f);
    unsigned r = (u + 0x7fffu + ((u >> 16) & 1u)) >> 16;
    return (ushort)r;
}

// ---------------- generic fp32 GEMM (small/sensitive ops): C = cS*(A@B) + eS*E + bias
__global__ __launch_bounds__(256)
void gemm_f32(const float* __restrict__ A, int lda, long sA,
              const float* __restrict__ B, int ldb, long sB,
              float* __restrict__ C, int ldc, long sC,
              int M, int N, int K,
              const float* __restrict__ bias,
              const float* __restrict__ E, int ldE, long sE, float eS,
              float cS, int relu, int accum)
{
    A += (long)blockIdx.z * sA;
    B += (long)blockIdx.z * sB;
    C += (long)blockIdx.z * sC;
    if (E) E += (long)blockIdx.z * sE;
    const int m0 = blockIdx.y * 64, n0 = blockIdx.x * 64;
    const int t = threadIdx.x;
    const int tx = t & 15, ty = t >> 4;
    __shared__ float As[16][64];
    __shared__ float Bs[16][64];
    float acc[4][4] = {};
    const int arow = t >> 2, akc = (t & 3) * 4;
    const int brow = t >> 4, bnc = (t & 15) * 4;
    for (int k0 = 0; k0 < K; k0 += 16) {
        float4 av = make_float4(0.f, 0.f, 0.f, 0.f);
        if (m0 + arow < M) av = *(const float4*)(A + (long)(m0 + arow) * lda + k0 + akc);
        As[akc + 0][arow] = av.x; As[akc + 1][arow] = av.y;
        As[akc + 2][arow] = av.z; As[akc + 3][arow] = av.w;
        float4 bv = *(const float4*)(B + (long)(k0 + brow) * ldb + n0 + bnc);
        *(float4*)&Bs[brow][bnc] = bv;
        __syncthreads();
#pragma unroll
        for (int kk = 0; kk < 16; ++kk) {
            float4 a4 = *(const float4*)&As[kk][ty * 4];
            float4 b4 = *(const float4*)&Bs[kk][tx * 4];
            float a[4] = {a4.x, a4.y, a4.z, a4.w};
            float b[4] = {b4.x, b4.y, b4.z, b4.w};
#pragma unroll
            for (int i = 0; i < 4; i++)
#pragma unroll
                for (int j = 0; j < 4; j++) acc[i][j] = fmaf(a[i], b[j], acc[i][j]);
        }
        __syncthreads();
    }
#pragma unroll
    for (int i = 0; i < 4; i++) {
        int m = m0 + ty * 4 + i;
        if (m < M) {
#pragma unroll
            for (int j = 0; j < 4; j++) {
                int n = n0 + tx * 4 + j;
                float v = cS * acc[i][j];
                if (E) v = fmaf(eS, E[(long)m * ldE + n], v);
                if (bias) v += bias[n];
                if (relu) v = fmaxf(v, 0.f);
                if (accum) C[(long)m * ldc + n] += v;
                else C[(long)m * ldc + n] = v;
            }
        }
    }
}

// ---------------- Bm GEMM: C(f32,[256][64]) = A(bf16,[256][256]) @ B(f32,[256][64]).
// Exact clone of gemm_f32's body (same As layout, same fmaf order -> bit-identical
// results) with the bf16->f32 conversion folded into A staging. Replaces k_b2f+gemm_f32.
__global__ __launch_bounds__(256)
void gemm_zb(const ushort* __restrict__ A, const float* __restrict__ B,
             float* __restrict__ C)
{
    A += (long)blockIdx.z * 65536;
    B += (long)blockIdx.z * 16384;
    C += (long)blockIdx.z * 16384;
    const int m0 = blockIdx.y * 64;
    const int t = threadIdx.x;
    const int tx = t & 15, ty = t >> 4;
    __shared__ float As[16][64];
    __shared__ float Bs[16][64];
    float acc[4][4] = {};
    const int arow = t >> 2, akc = (t & 3) * 4;
    const int brow = t >> 4, bnc = (t & 15) * 4;
    for (int k0 = 0; k0 < 256; k0 += 16) {
        ushort4 av = *(const ushort4*)(A + (long)(m0 + arow) * 256 + k0 + akc);
        As[akc + 0][arow] = bf2f(av.x); As[akc + 1][arow] = bf2f(av.y);
        As[akc + 2][arow] = bf2f(av.z); As[akc + 3][arow] = bf2f(av.w);
        float4 bv = *(const float4*)(B + (long)(k0 + brow) * 64 + bnc);
        *(float4*)&Bs[brow][bnc] = bv;
        __syncthreads();
#pragma unroll
        for (int kk = 0; kk < 16; ++kk) {
            float4 a4 = *(const float4*)&As[kk][ty * 4];
            float4 b4 = *(const float4*)&Bs[kk][tx * 4];
            float a[4] = {a4.x, a4.y, a4.z, a4.w};
            float b[4] = {b4.x, b4.y, b4.z, b4.w};
#pragma unroll
            for (int i = 0; i < 4; i++)
#pragma unroll
                for (int j = 0; j < 4; j++) acc[i][j] = fmaf(a[i], b[j], acc[i][j]);
        }
        __syncthreads();
    }
#pragma unroll
    for (int i = 0; i < 4; i++) {
        int m = m0 + ty * 4 + i;
#pragma unroll
        for (int j = 0; j < 4; j++) {
            int n = tx * 4 + j;
            C[(long)m * 64 + n] = acc[i][j];
        }
    }
}

// ---------------- bf16 MFMA GEMM: C(fp32) = A(bf16,[M][K]) @ Bt(bf16,[N][K])^T
// v2: register prefetch of next K-tile, bijective XCD swizzle, TM=64 tiles.
template<int MT, int NT, int WROWS, int WCOLS>
__global__ __launch_bounds__(256)
void gemm_mfma(const ushort* __restrict__ A, int lda, long sA,
               const ushort* __restrict__ Bt, int ldb, long sB,
               float* __restrict__ C, int ldc, long sC,
               int M, int K,
               const float* __restrict__ bias, int relu, int accum)
{
    constexpr int TM = MT * 16 * WROWS;
    constexpr int TN = NT * 16 * WCOLS;
    constexpr int BKP = 40;
    constexpr int AIT = TM / 64;
    constexpr int BIT = TN / 64;
    __shared__ ushort As[TM * BKP];
    __shared__ ushort Bs[TN * BKP];
    A  += (long)blockIdx.z * sA;
    Bt += (long)blockIdx.z * sB;
    C  += (long)blockIdx.z * sC;
    const int t = threadIdx.x;
    const int nwg = gridDim.x * gridDim.y;
    const int flat = blockIdx.y * gridDim.x + blockIdx.x;
    const int q8 = nwg >> 3, r8 = nwg & 7;
    const int xcd = flat & 7, idx = flat >> 3;
    const int swz = (xcd < r8) ? (xcd * (q8 + 1) + idx)
                               : (r8 * (q8 + 1) + (xcd - r8) * q8 + idx);
    const int m0 = (swz / gridDim.x) * TM;
    const int n0 = (swz % gridDim.x) * TN;
    const int w = t >> 6, l = t & 63;
    const int wm = (w / WCOLS) * (MT * 16), wn = (w % WCOLS) * (NT * 16);
    const int lr = l & 15;
    const int lk = (l >> 4) * 8;
    const int srow = t >> 2, skc = (t & 3) * 8;
    f4 acc[MT][NT] = {};
    s8b pa[AIT], pb[BIT];
#pragma unroll
    for (int i = 0; i < AIT; i++)
        pa[i] = *(const s8b*)(A + (long)(m0 + srow + i * 64) * lda + skc);
#pragma unroll
    for (int i = 0; i < BIT; i++)
        pb[i] = *(const s8b*)(Bt + (long)(n0 + srow + i * 64) * ldb + skc);
    for (int k0 = 0; k0 < K; k0 += 32) {
        __syncthreads();
#pragma unroll
        for (int i = 0; i < AIT; i++)
            *(s8b*)(&As[(srow + i * 64) * BKP + skc]) = pa[i];
#pragma unroll
        for (int i = 0; i < BIT; i++)
            *(s8b*)(&Bs[(srow + i * 64) * BKP + skc]) = pb[i];
        if (k0 + 32 < K) {
#pragma unroll
            for (int i = 0; i < AIT; i++)
                pa[i] = *(const s8b*)(A + (long)(m0 + srow + i * 64) * lda + k0 + 32 + skc);
#pragma unroll
            for (int i = 0; i < BIT; i++)
                pb[i] = *(const s8b*)(Bt + (long)(n0 + srow + i * 64) * ldb + k0 + 32 + skc);
        }
        __syncthreads();
        s8b af[MT], bf[NT];
#pragma unroll
        for (int i = 0; i < MT; i++) af[i] = *(const s8b*)(&As[(wm + i * 16 + lr) * BKP + lk]);
#pragma unroll
        for (int j = 0; j < NT; j++) bf[j] = *(const s8b*)(&Bs[(wn + j * 16 + lr) * BKP + lk]);
#pragma unroll
        for (int i = 0; i < MT; i++)
#pragma unroll
            for (int j = 0; j < NT; j++)
                acc[i][j] = __builtin_amdgcn_mfma_f32_16x16x32_bf16(af[i], bf[j], acc[i][j], 0, 0, 0);
    }
    const int orow = (l >> 4) * 4;
#pragma unroll
    for (int i = 0; i < MT; i++) {
#pragma unroll
        for (int r = 0; r < 4; r++) {
            int m = m0 + wm + i * 16 + orow + r;
            if (m < M) {
#pragma unroll
                for (int j = 0; j < NT; j++) {
                    int n = n0 + wn + j * 16 + lr;
                    float vv = acc[i][j][r];
                    if (bias) vv += bias[n];
                    if (relu) vv = fmaxf(vv, 0.f);
                    if (accum) C[(long)m * ldc + n] += vv;
                    else C[(long)m * ldc + n] = vv;
                }
            }
        }
    }
}

// ---------------- fc1 GEMM with fused fp32->bf16 A conversion.
// v2: DEPTH-2 register prefetch ring (pa[2], pb[2][2]) — A streams cold from HBM
// (~900cyc); 1-step lookahead (~200cyc of compute) couldn't cover it (measured
// 68us, VALUBusy 10%). 2-step lookahead issues loads ~2 k-steps (~450cyc) early.
// LDS values/order bit-identical to v1.
__global__ __launch_bounds__(256)
void gemm_fc1(const float* __restrict__ A, const ushort* __restrict__ Bt,
              float* __restrict__ C, const float* __restrict__ bias)
{
    constexpr int BKP = 40;
    __shared__ ushort As[64 * BKP];
    __shared__ ushort Bs[128 * BKP];
    const int t = threadIdx.x;
    const int nwg = gridDim.x * gridDim.y;
    const int flat = blockIdx.y * gridDim.x + blockIdx.x;
    const int q8 = nwg >> 3, r8 = nwg & 7;
    const int xcd = flat & 7, idx = flat >> 3;
    const int swz = (xcd < r8) ? (xcd * (q8 + 1) + idx)
                               : (r8 * (q8 + 1) + (xcd - r8) * q8 + idx);
    const int m0 = (swz / gridDim.x) * 64;
    const int n0 = (swz % gridDim.x) * 128;
    const int w = t >> 6, l = t & 63;
    const int wm = (w >> 1) * 32, wn = (w & 1) * 64;
    const int lr = l & 15, lk = (l >> 4) * 8;
    const int srow = t >> 2, skc = (t & 3) * 8;
    int ar = m0 + srow; if (ar > 14999) ar = 14999;
    const float* arow_p = A + (long)ar * 1024;
    f4 acc[2][4] = {};
    auto cvt8 = [&](const float* p) {
        float4 v0 = *(const float4*)p;
        float4 v1 = *(const float4*)(p + 4);
        s8b r;
        ((ushort*)&r)[0] = f2bf(v0.x); ((ushort*)&r)[1] = f2bf(v0.y);
        ((ushort*)&r)[2] = f2bf(v0.z); ((ushort*)&r)[3] = f2bf(v0.w);
        ((ushort*)&r)[4] = f2bf(v1.x); ((ushort*)&r)[5] = f2bf(v1.y);
        ((ushort*)&r)[6] = f2bf(v1.z); ((ushort*)&r)[7] = f2bf(v1.w);
        return r;
    };
    // depth-2 prefetch ring: slot s holds k-step (k0 where (k0>>5)&1 == s)
    s8b pa[2];
    s8b pb[2][2];
    pa[0] = cvt8(arow_p + skc);
    pa[1] = cvt8(arow_p + 32 + skc);
#pragma unroll
    for (int i = 0; i < 2; i++) {
        pb[0][i] = *(const s8b*)(Bt + (long)(n0 + srow + i * 64) * 1024 + skc);
        pb[1][i] = *(const s8b*)(Bt + (long)(n0 + srow + i * 64) * 1024 + 32 + skc);
    }
    for (int k0 = 0; k0 < 1024; k0 += 32) {
        const int slot = (k0 >> 5) & 1;
        __syncthreads();
        *(s8b*)(&As[srow * BKP + skc]) = pa[slot];
#pragma unroll
        for (int i = 0; i < 2; i++)
            *(s8b*)(&Bs[(srow + i * 64) * BKP + skc]) = pb[slot][i];
        if (k0 + 64 < 1024) {   // refill this slot for k-step k0+64 (2 ahead)
            pa[slot] = cvt8(arow_p + k0 + 64 + skc);
#pragma unroll
            for (int i = 0; i < 2; i++)
                pb[slot][i] = *(const s8b*)(Bt + (long)(n0 + srow + i * 64) * 1024 + k0 + 64 + skc);
        }
        __syncthreads();
        s8b af[2], bf[4];
#pragma unroll
        for (int i = 0; i < 2; i++) af[i] = *(const s8b*)(&As[(wm + i * 16 + lr) * BKP + lk]);
#pragma unroll
        for (int j = 0; j < 4; j++) bf[j] = *(const s8b*)(&Bs[(wn + j * 16 + lr) * BKP + lk]);
#pragma unroll
        for (int i = 0; i < 2; i++)
#pragma unroll
            for (int j = 0; j < 4; j++)
                acc[i][j] = __builtin_amdgcn_mfma_f32_16x16x32_bf16(af[i], bf[j], acc[i][j], 0, 0, 0);
    }
    const int orow = (l >> 4) * 4;
#pragma unroll
    for (int i = 0; i < 2; i++) {
#pragma unroll
        for (int r = 0; r < 4; r++) {
            int m = m0 + wm + i * 16 + orow + r;
            if (m < 15000) {
#pragma unroll
                for (int j = 0; j < 4; j++) {
                    int n = n0 + wn + j * 16 + lr;
                    float vv = acc[i][j][r] + bias[n];
                    vv = fmaxf(vv, 0.f);
                    C[(long)m * 512 + n] = vv;
                }
            }
        }
    }
}

// ---------------- bf16-in/bf16-out MFMA GEMM, B row-major [K][N]: C16 = bf16(cS*(A@B) + eS*E16)
// v2: register prefetch of next K-tile; rotation-swizzled B^T staging.
__global__ __launch_bounds__(256)
void gemm_nn16(const ushort* __restrict__ A, const ushort* __restrict__ B,
               const ushort* __restrict__ E, ushort* __restrict__ C,
               int N, int K, float cS, float eS, long sAB)
{
    __shared__ ushort As[64 * 40];
    __shared__ ushort Bs[64 * 40];
    A += (long)blockIdx.z * sAB;
    B += (long)blockIdx.z * sAB;
    if (E) E += (long)blockIdx.z * sAB;
    C += (long)blockIdx.z * sAB;
    const int t = threadIdx.x;
    const int m0 = blockIdx.y * 64, n0 = blockIdx.x * 64;
    const int w = t >> 6, l = t & 63;
    const int wm = (w >> 1) * 32, wn = (w & 1) * 32;
    const int lr = l & 15, lk = (l >> 4) * 8;
    const int quad = l >> 4;
    const int arow = t >> 2, akc = (t & 3) * 8;
    const int bkk = t >> 3, bnc = (t & 7) * 8;
    const int bcolp = (bkk + ((bnc >> 3) & 3) * 8) & 31;   // rot by (n>>3)&3
    f4 acc[2][2] = {};
    s8b pa = *(const s8b*)(A + (long)(m0 + arow) * K + akc);
    s8b pb = *(const s8b*)(B + (long)bkk * N + n0 + bnc);
    for (int k0 = 0; k0 < K; k0 += 32) {
        __syncthreads();
        *(s8b*)(&As[arow * 40 + akc]) = pa;
#pragma unroll
        for (int j = 0; j < 8; j++) Bs[(bnc + j) * 40 + bcolp] = ((ushort*)&pb)[j];
        if (k0 + 32 < K) {
            pa = *(const s8b*)(A + (long)(m0 + arow) * K + k0 + 32 + akc);
            pb = *(const s8b*)(B + (long)(k0 + 32 + bkk) * N + n0 + bnc);
        }
        __syncthreads();
        s8b af[2], bf[2];
#pragma unroll
        for (int i = 0; i < 2; i++) af[i] = *(const s8b*)(&As[(wm + i * 16 + lr) * 40 + lk]);
#pragma unroll
        for (int j = 0; j < 2; j++) {
            int n = wn + j * 16 + lr;
            int cb = ((quad + ((n >> 3) & 3)) & 3) * 8;
            bf[j] = *(const s8b*)(&Bs[n * 40 + cb]);
        }
#pragma unroll
        for (int i = 0; i < 2; i++)
#pragma unroll
            for (int j = 0; j < 2; j++)
                acc[i][j] = __builtin_amdgcn_mfma_f32_16x16x32_bf16(af[i], bf[j], acc[i][j], 0, 0, 0);
    }
    const int orow = (l >> 4) * 4;
#pragma unroll
    for (int i = 0; i < 2; i++)
#pragma unroll
        for (int r = 0; r < 4; r++) {
            int m = m0 + wm + i * 16 + orow + r;
#pragma unroll
            for (int j = 0; j < 2; j++) {
                int n = wn + j * 16 + lr;
                float vv = cS * acc[i][j][r];
                if (E) vv = fmaf(eS, bf2f(E[(long)m * N + n0 + n]), vv);
                C[(long)m * N + n0 + n] = f2bf(vv);
            }
        }
}

// ---------------- qkv MFMA GEMM, scatter into bf16 q/k/v [head][NPQ][64], q scaled 1/8
// v2: register prefetch of next K-tile + bijective XCD swizzle.
__global__ __launch_bounds__(256)
void gemm_qkv_mfma(const ushort* __restrict__ A, const ushort* __restrict__ Bt,
                   ushort* __restrict__ qo, ushort* __restrict__ ko, ushort* __restrict__ vo)
{
    constexpr int BKP = 40;
    __shared__ ushort As[128 * BKP];
    __shared__ ushort Bs[128 * BKP];
    const int t = threadIdx.x;
    const int nwg = gridDim.x * gridDim.y;
    const int flat = blockIdx.y * gridDim.x + blockIdx.x;
    const int q8 = nwg >> 3, r8 = nwg & 7;
    const int xcd = flat & 7, idx = flat >> 3;
    const int swz = (xcd < r8) ? (xcd * (q8 + 1) + idx)
                               : (r8 * (q8 + 1) + (xcd - r8) * q8 + idx);
    const int m0 = (swz / gridDim.x) * 128;
    const int n0 = (swz % gridDim.x) * 128;
    const int w = t >> 6, l = t & 63;
    const int wm = (w >> 1) * 64, wn = (w & 1) * 64;
    const int lr = l & 15;
    const int lk = (l >> 4) * 8;
    const int srow = t >> 2, skc = (t & 3) * 8;
    f4 acc[4][4] = {};
    s8b pa[2], pb[2];
#pragma unroll
    for (int i = 0; i < 2; i++) {
        pa[i] = *(const s8b*)(A + (long)(m0 + srow + i * 64) * 512 + skc);
        pb[i] = *(const s8b*)(Bt + (long)(n0 + srow + i * 64) * 512 + skc);
    }
    for (int k0 = 0; k0 < 512; k0 += 32) {
        __syncthreads();
#pragma unroll
        for (int i = 0; i < 2; i++) {
            *(s8b*)(&As[(srow + i * 64) * BKP + skc]) = pa[i];
            *(s8b*)(&Bs[(srow + i * 64) * BKP + skc]) = pb[i];
        }
        if (k0 + 32 < 512) {
#pragma unroll
            for (int i = 0; i < 2; i++) {
                pa[i] = *(const s8b*)(A + (long)(m0 + srow + i * 64) * 512 + k0 + 32 + skc);
                pb[i] = *(const s8b*)(Bt + (long)(n0 + srow + i * 64) * 512 + k0 + 32 + skc);
            }
        }
        __syncthreads();
        s8b af[4], bf[4];
#pragma unroll
        for (int i = 0; i < 4; i++) af[i] = *(const s8b*)(&As[(wm + i * 16 + lr) * BKP + lk]);
#pragma unroll
        for (int j = 0; j < 4; j++) bf[j] = *(const s8b*)(&Bs[(wn + j * 16 + lr) * BKP + lk]);
#pragma unroll
        for (int i = 0; i < 4; i++)
#pragma unroll
            for (int j = 0; j < 4; j++)
                acc[i][j] = __builtin_amdgcn_mfma_f32_16x16x32_bf16(af[i], bf[j], acc[i][j], 0, 0, 0);
    }
    const int orow = (l >> 4) * 4;
#pragma unroll
    for (int i = 0; i < 4; i++) {
#pragma unroll
        for (int r = 0; r < 4; r++) {
            int m = m0 + wm + i * 16 + orow + r;
#pragma unroll
            for (int j = 0; j < 4; j++) {
                int col = n0 + wn + j * 16 + lr;
                int which = col >> 9, h = (col >> 6) & 7, d = col & 63;
                float vv = acc[i][j][r];
                if (which == 0) vv *= 0.125f;
                ushort* dst = which == 0 ? qo : (which == 1 ? ko : vo);
                dst[((long)h * NPQ + m) * 64 + d] = f2bf(vv);
            }
        }
    }
}

// ---------------- flash a3@v, MAX-FREE (scores |s|<~1): p=exp(s), lsum via ones-MFMA, no shuffles.
// v2: __launch_bounds__(256,3) for VGPR headroom; register prefetch of next-sub
// V row + K fragments one sub ahead so global latency hides under compute+barriers.
__global__ __launch_bounds__(256, 3)
void k_flash_a3v(const ushort* __restrict__ qlb, const ushort* __restrict__ kg,
                 const ushort* __restrict__ vg,
                 float* __restrict__ pacc, float* __restrict__ pml)
{
    const int c = blockIdx.x;
    const int qt = blockIdx.y;
    const int h = blockIdx.z;
    const int t = threadIdx.x;
    const int w = t >> 6, lane = t & 63;
    const int quad = lane >> 4, l16 = lane & 15;
    const s8b vones = {0x3F80, 0x3F80, 0x3F80, 0x3F80, 0x3F80, 0x3F80, 0x3F80, 0x3F80};

    __shared__ union {
        struct { ushort Vt[64][40]; ushort Ps[128][40]; } s;
        float Os[128][68];
    } L;

    s8b aq[2][2];
    const ushort* qbase = qlb + ((long)h * 256 + qt * 128 + w * 32) * 64;
#pragma unroll
    for (int mi = 0; mi < 2; mi++)
#pragma unroll
        for (int kf = 0; kf < 2; kf++)
            aq[mi][kf] = *(const s8b*)(qbase + (mi * 16 + l16) * 64 + kf * 32 + quad * 8);

    f4 oacc[2][4] = {};
    f4 lacc[2] = {};

    const ushort* kh = kg + (long)h * NPQ * 64;
    const ushort* vh = vg + (long)h * NPQ * 64;
    const int key0c = c * 256;

    const int vkk = (t >> 3) & 31;
    const int vdc = (t & 7) * 8;
    const int vcolp = (vkk + ((vdc >> 3) & 3) * 8) & 31;

    s8b vvN = *(const s8b*)(vh + (long)(key0c + vkk) * 64 + vdc);
    s8b bqN[2][2];
#pragma unroll
    for (int nj = 0; nj < 2; nj++)
#pragma unroll
        for (int kf = 0; kf < 2; kf++)
            bqN[nj][kf] = *(const s8b*)(kh + (long)(key0c + nj * 16 + l16) * 64 + kf * 32 + quad * 8);

#pragma unroll
    for (int sub = 0; sub < 8; sub++) {
        int key0 = key0c + sub * 32;
        s8b vvC = vvN;
        s8b bq[2][2];
#pragma unroll
        for (int nj = 0; nj < 2; nj++)
#pragma unroll
            for (int kf = 0; kf < 2; kf++) bq[nj][kf] = bqN[nj][kf];
        if (sub < 7) {
            vvN = *(const s8b*)(vh + (long)(key0 + 32 + vkk) * 64 + vdc);
#pragma unroll
            for (int nj = 0; nj < 2; nj++)
#pragma unroll
                for (int kf = 0; kf < 2; kf++)
                    bqN[nj][kf] = *(const s8b*)(kh + (long)(key0 + 32 + nj * 16 + l16) * 64 + kf * 32 + quad * 8);
        }
        __syncthreads();
        {
#pragma unroll
            for (int j = 0; j < 8; j++) L.s.Vt[vdc + j][vcolp] = ((ushort*)&vvC)[j];
        }
        f4 sacc[2][2] = {};
#pragma unroll
        for (int mi = 0; mi < 2; mi++)
#pragma unroll
            for (int nj = 0; nj < 2; nj++) {
                sacc[mi][nj] = __builtin_amdgcn_mfma_f32_16x16x32_bf16(aq[mi][0], bq[nj][0], sacc[mi][nj], 0, 0, 0);
                sacc[mi][nj] = __builtin_amdgcn_mfma_f32_16x16x32_bf16(aq[mi][1], bq[nj][1], sacc[mi][nj], 0, 0, 0);
            }
#pragma unroll
        for (int mi = 0; mi < 2; mi++)
#pragma unroll
            for (int r = 0; r < 4; r++) {
                int row = w * 32 + mi * 16 + quad * 4 + r;
                L.s.Ps[row][l16]      = f2bf(__expf(sacc[mi][0][r]));
                L.s.Ps[row][16 + l16] = f2bf(__expf(sacc[mi][1][r]));
            }
        __syncthreads();
        s8b ap[2], bv[4];
#pragma unroll
        for (int mi = 0; mi < 2; mi++)
            ap[mi] = *(const s8b*)(&L.s.Ps[w * 32 + mi * 16 + l16][quad * 8]);
#pragma unroll
        for (int dj = 0; dj < 4; dj++) {
            int d = dj * 16 + l16;
            int rot = (d >> 3) & 3;
            int cb = ((quad + rot) & 3) * 8;
            bv[dj] = *(const s8b*)(&L.s.Vt[d][cb]);
        }
#pragma unroll
        for (int mi = 0; mi < 2; mi++) {
#pragma unroll
            for (int dj = 0; dj < 4; dj++)
                oacc[mi][dj] = __builtin_amdgcn_mfma_f32_16x16x32_bf16(ap[mi], bv[dj], oacc[mi][dj], 0, 0, 0);
            lacc[mi] = __builtin_amdgcn_mfma_f32_16x16x32_bf16(ap[mi], vones, lacc[mi], 0, 0, 0);
        }
    }
    __syncthreads();
#pragma unroll
    for (int mi = 0; mi < 2; mi++)
#pragma unroll
        for (int dj = 0; dj < 4; dj++)
#pragma unroll
            for (int r = 0; r < 4; r++)
                L.Os[w * 32 + mi * 16 + quad * 4 + r][dj * 16 + l16] = oacc[mi][dj][r];
    long pbase = (long)(h * 60 + c);
    if (l16 == 0) {
#pragma unroll
        for (int mi = 0; mi < 2; mi++)
#pragma unroll
            for (int r = 0; r < 4; r++) {
                int i = qt * 128 + w * 32 + mi * 16 + quad * 4 + r;
                pml[pbase * 512 + i] = 0.f;
                pml[pbase * 512 + 256 + i] = lacc[mi][r];
            }
    }
    __syncthreads();
    float* pc = pacc + pbase * 16384 + qt * 128;
    int d = t >> 2, ig = t & 3;
#pragma unroll
    for (int u = 0; u < 8; u++) {
        int i0 = ig * 32 + u * 4;
        float4 v4 = make_float4(L.Os[i0][d], L.Os[i0 + 1][d], L.Os[i0 + 2][d], L.Os[i0 + 3][d]);
        *(float4*)(pc + (long)d * 256 + i0) = v4;
    }
}

// ---------------- fused sim1+softmax+@BmT attention + res-conv; MAX-FREE single pass,
// wave-local Ps (no barriers in K-loop), lsum via ones-MFMA (no shuffles).
// v3 (proven 48us): __launch_bounds__(256,3); register dbuf of next-sub K frags;
// bv issued at sub top; conv uses vr[48] register window from LDS.
__global__ __launch_bounds__(256, 3)
void k_attn1(const ushort* __restrict__ qg, const ushort* __restrict__ klb,
             const ushort* __restrict__ BmT, const ushort* __restrict__ vg,
             const float* __restrict__ rw, ushort* __restrict__ ohb)
{
    const int m0 = blockIdx.x * 128;
    const int h = blockIdx.y;
    const int t = threadIdx.x;
    const int w = t >> 6, lane = t & 63;
    const int quad = lane >> 4, l16 = lane & 15;
    const s8b vones = {0x3F80, 0x3F80, 0x3F80, 0x3F80, 0x3F80, 0x3F80, 0x3F80, 0x3F80};

    __shared__ union {
        ushort Ps[2][128][40];
        ushort Os[128][68];
    } L;
    __shared__ __attribute__((aligned(16))) ushort Vs[160][64];  // v rows [214+m0, 214+m0+160)

    const ushort* vh = vg + (long)h * NPQ * 64;
    {
        const ushort* srcw = vh + (long)(214 + m0 + w * 40) * 64 + lane * 8;
        ushort* dstw = &Vs[w * 40][0];
#pragma unroll
        for (int it = 0; it < 5; it++)
            __builtin_amdgcn_global_load_lds(
                (const __attribute__((address_space(1))) void*)(srcw + it * 512),
                (__attribute__((address_space(3))) void*)(dstw + it * 512),
                16, 0, 0);
    }

    s8b aq[2][2];
    const ushort* qbase = qg + ((long)h * NPQ + 230 + m0 + w * 32) * 64;
#pragma unroll
    for (int mi = 0; mi < 2; mi++)
#pragma unroll
        for (int kf = 0; kf < 2; kf++)
            aq[mi][kf] = *(const s8b*)(qbase + (mi * 16 + l16) * 64 + kf * 32 + quad * 8);

    const ushort* kh = klb + (long)h * 16384;
    const ushort* bmt = BmT + (long)h * 16384;

    s8b bqN[2][2];
#pragma unroll
    for (int nj = 0; nj < 2; nj++)
#pragma unroll
        for (int kf = 0; kf < 2; kf++)
            bqN[nj][kf] = *(const s8b*)(kh + (long)(nj * 16 + l16) * 64 + kf * 32 + quad * 8);

    f4 oacc[2][4] = {};
    f4 lacc[2] = {};
#pragma unroll
    for (int sub = 0; sub < 8; sub++) {
        int key0 = sub * 32;
        s8b bq[2][2];
#pragma unroll
        for (int nj = 0; nj < 2; nj++)
#pragma unroll
            for (int kf = 0; kf < 2; kf++) bq[nj][kf] = bqN[nj][kf];
        if (sub < 7) {
#pragma unroll
            for (int nj = 0; nj < 2; nj++)
#pragma unroll
                for (int kf = 0; kf < 2; kf++)
                    bqN[nj][kf] = *(const s8b*)(kh + (long)(key0 + 32 + nj * 16 + l16) * 64 + kf * 32 + quad * 8);
        }
        s8b bv[4];
#pragma unroll
        for (int dj = 0; dj < 4; dj++)
            bv[dj] = *(const s8b*)(bmt + (long)(dj * 16 + l16) * 256 + key0 + quad * 8);
        f4 sacc[2][2] = {};
#pragma unroll
        for (int mi = 0; mi < 2; mi++)
#pragma unroll
            for (int nj = 0; nj < 2; nj++) {
                sacc[mi][nj] = __builtin_amdgcn_mfma_f32_16x16x32_bf16(aq[mi][0], bq[nj][0], sacc[mi][nj], 0, 0, 0);
                sacc[mi][nj] = __builtin_amdgcn_mfma_f32_16x16x32_bf16(aq[mi][1], bq[nj][1], sacc[mi][nj], 0, 0, 0);
            }
        int par = sub & 1;
#pragma unroll
        for (int mi = 0; mi < 2; mi++)
#pragma unroll
            for (int r = 0; r < 4; r++) {
                int row = w * 32 + mi * 16 + quad * 4 + r;
                L.Ps[par][row][l16]      = f2bf(__expf(sacc[mi][0][r]));
                L.Ps[par][row][16 + l16] = f2bf(__expf(sacc[mi][1][r]));
            }
        s8b ap[2];
#pragma unroll
        for (int mi = 0; mi < 2; mi++)
            ap[mi] = *(const s8b*)(&L.Ps[par][w * 32 + mi * 16 + l16][quad * 8]);
#pragma unroll
        for (int mi = 0; mi < 2; mi++) {
#pragma unroll
            for (int dj = 0; dj < 4; dj++)
                oacc[mi][dj] = __builtin_amdgcn_mfma_f32_16x16x32_bf16(ap[mi], bv[dj], oacc[mi][dj], 0, 0, 0);
            lacc[mi] = __builtin_amdgcn_mfma_f32_16x16x32_bf16(ap[mi], vones, lacc[mi], 0, 0, 0);
        }
    }
    __syncthreads();

    if (214 + m0 + 160 > NP) {
        for (int r = w * 32; r < w * 32 + 64 && r < 160; ++r)
            if (214 + m0 + r >= NP) Vs[r][lane] = 0;
    }

#pragma unroll
    for (int mi = 0; mi < 2; mi++)
#pragma unroll
        for (int r = 0; r < 4; r++) {
            float inv = 1.f / lacc[mi][r];
            int row = w * 32 + mi * 16 + quad * 4 + r;
#pragma unroll
            for (int dj = 0; dj < 4; dj++)
                L.Os[row][dj * 16 + l16] = f2bf(oacc[mi][dj][r] * inv);
        }
    float rwf[33];
#pragma unroll
    for (int kk = 0; kk < 33; kk++) rwf[kk] = rw[h * 33 + kk];
#pragma unroll
    for (int half = 0; half < 2; half++) {
        const int rbase = w * 32 + half * 16;
        float vr[48];
#pragma unroll
        for (int s = 0; s < 48; s++) vr[s] = bf2f(Vs[rbase + s][lane]);
        float conv[16];
#pragma unroll
        for (int i = 0; i < 16; i++) conv[i] = 0.f;
#pragma unroll
        for (int kk = 0; kk < 33; kk++) {
            float wk = rwf[kk];
#pragma unroll
            for (int i = 0; i < 16; i++) conv[i] = fmaf(wk, vr[i + kk], conv[i]);
        }
        int t0 = m0 + rbase;
#pragma unroll
        for (int i = 0; i < 16; i++) {
            int tk = t0 + i;
            if (tk < NTOK) {
                float val = bf2f(L.Os[rbase + i][lane]) + conv[i];
                ohb[(long)tk * 512 + h * 64 + lane] = f2bf(val);
            }
        }
    }
}

// ---------------- layernorm over 512, writes bf16 xln (first `pad` rows zero)
__global__ __launch_bounds__(256)
void k_layernorm(const float* __restrict__ h, ushort* __restrict__ xln,
                 const float* __restrict__ g, const float* __restrict__ b, int pad)
{
    int row = blockIdx.x, t = threadIdx.x;
    if (row < pad) {
        xln[(long)row * 512 + t] = 0;
        xln[(long)row * 512 + t + 256] = 0;
        return;
    }
    const float* src = h + (long)(row - pad) * 512;
    float x1 = src[t], x2 = src[t + 256];
    float s = x1 + x2, q = x1 * x1 + x2 * x2;
    __shared__ float rs[4], rq[4], st[2];
    int wid = t >> 6, lane = t & 63;
#pragma unroll
    for (int o = 32; o > 0; o >>= 1) { s += __shfl_down(s, o); q += __shfl_down(q, o); }
    if (lane == 0) { rs[wid] = s; rq[wid] = q; }
    __syncthreads();
    if (t == 0) {
        float S = rs[0] + rs[1] + rs[2] + rs[3];
        float Q = rq[0] + rq[1] + rq[2] + rq[3];
        float mean = S / 512.f;
        float var = Q / 512.f - mean * mean;
        st[0] = mean; st[1] = rsqrtf(var + 1e-5f);
    }
    __syncthreads();
    float mean = st[0], rstd = st[1];
    xln[(long)row * 512 + t] = f2bf((x1 - mean) * rstd * g[t] + b[t]);
    xln[(long)row * 512 + t + 256] = f2bf((x2 - mean) * rstd * g[t + 256] + b[t + 256]);
}

__global__ __launch_bounds__(256)
void k_padcls(float* __restrict__ hbuf, const float* __restrict__ cls)
{
    int i = blockIdx.x, t = threadIdx.x;
    if (i == 0) { hbuf[t] = cls[t]; hbuf[t + 256] = cls[t + 256]; }
    else {
        hbuf[(long)(15000 + i) * 512 + t] = hbuf[(long)i * 512 + t];
        hbuf[(long)(15000 + i) * 512 + t + 256] = hbuf[(long)i * 512 + t + 256];
    }
}

__global__ __launch_bounds__(256)
void k_wT(const float* __restrict__ Wm, ushort* __restrict__ Wt, int K, int N, long sW, long sWt)
{
    Wm += (long)blockIdx.z * sW; Wt += (long)blockIdx.z * sWt;
    __shared__ float tile[32][33];
    int tx = threadIdx.x & 31, ty = threadIdx.x >> 5;
    int n0 = blockIdx.x * 32, k0 = blockIdx.y * 32;
#pragma unroll
    for (int u = 0; u < 4; u++) tile[ty + u * 8][tx] = Wm[(long)(k0 + ty + u * 8) * N + n0 + tx];
    __syncthreads();
#pragma unroll
    for (int u = 0; u < 4; u++) Wt[(long)(n0 + ty + u * 8) * K + k0 + tx] = f2bf(tile[tx][ty + u * 8]);
}

__global__ __launch_bounds__(64)
void k_landmarks(const ushort* __restrict__ q, const ushort* __restrict__ k,
                 float* __restrict__ ql, ushort* __restrict__ qlb,
                 float* __restrict__ klT, ushort* __restrict__ klb,
                 unsigned* __restrict__ scal)
{
    int i = blockIdx.x, h = blockIdx.y, d = threadIdx.x;
    if (i == 0 && h == 0 && d == 0) { scal[0] = 0u; scal[1] = 0u; }
    long base = ((long)h * NPQ + (long)i * 60) * 64 + d;
    float sq = 0.f, sk = 0.f;
    for (int j = 0; j < 60; j++) { sq += bf2f(q[base + j * 64]); sk += bf2f(k[base + j * 64]); }
    float qv = sq / 60.f, kv = sk / 60.f;
    ql[((long)h * 256 + i) * 64 + d] = qv;
    qlb[((long)h * 256 + i) * 64 + d] = f2bf(qv);
    klT[((long)h * 64 + d) * 256 + i] = kv;
    klb[((long)h * 256 + i) * 64 + d] = f2bf(kv);
}

__global__ __launch_bounds__(256)
void k_softmax256(float* __restrict__ X, ushort* __restrict__ X16, long headStride)
{
    float* row = X + (long)blockIdx.y * headStride + (long)blockIdx.x * 256;
    int t = threadIdx.x, wid = t >> 6, lane = t & 63;
    float x = row[t];
    __shared__ float rm[4], rsum[4], fin[2];
    float m = x;
#pragma unroll
    for (int o = 32; o > 0; o >>= 1) m = fmaxf(m, __shfl_down(m, o));
    if (lane == 0) rm[wid] = m;
    __syncthreads();
    if (t == 0) fin[0] = fmaxf(fmaxf(rm[0], rm[1]), fmaxf(rm[2], rm[3]));
    __syncthreads();
    float e = __expf(x - fin[0]);
    float s = e;
#pragma unroll
    for (int o = 32; o > 0; o >>= 1) s += __shfl_down(s, o);
    if (lane == 0) rsum[wid] = s;
    __syncthreads();
    if (t == 0) fin[1] = rsum[0] + rsum[1] + rsum[2] + rsum[3];
    __syncthreads();
    float v = e / fin[1];
    row[t] = v;
    if (X16) X16[(long)blockIdx.y * headStride + (long)blockIdx.x * 256 + t] = f2bf(v);
}

__global__ __launch_bounds__(256)
void k_colmax(const float* __restrict__ a2, unsigned* __restrict__ scal)
{
    int h = blockIdx.x, t = threadIdx.x, wid = t >> 6, lane = t & 63;
    const float* A = a2 + (long)h * 65536;
    float cs = 0.f, rs = 0.f;
    for (int i = 0; i < 256; i++) cs += A[(long)i * 256 + t];
    for (int j = 0; j < 256; j++) rs += A[(long)t * 256 + j];
    __shared__ float r1[4], r2[4];
    float m1v = cs, m2v = rs;
#pragma unroll
    for (int o = 32; o > 0; o >>= 1) {
        m1v = fmaxf(m1v, __shfl_down(m1v, o));
        m2v = fmaxf(m2v, __shfl_down(m2v, o));
    }
    if (lane == 0) { r1[wid] = m1v; r2[wid] = m2v; }
    __syncthreads();
    if (t == 0) {
        float a = fmaxf(fmaxf(r1[0], r1[1]), fmaxf(r1[2], r1[3]));
        float b = fmaxf(fmaxf(r2[0], r2[1]), fmaxf(r2[2], r2[3]));
        atomicMax(scal + 0, __float_as_uint(a));
        atomicMax(scal + 1, __float_as_uint(b));
    }
}

__global__ __launch_bounds__(256)
void k_zinit(const float* __restrict__ a2, ushort* __restrict__ zb, const unsigned* __restrict__ scal)
{
    float s = 1.f / (__uint_as_float(scal[0]) * __uint_as_float(scal[1]));
    const float* A = a2 + (long)blockIdx.z * 65536;
    ushort* Z = zb + (long)blockIdx.z * 65536;
    __shared__ float tile[32][33];
    int tx = threadIdx.x & 31, ty = threadIdx.x >> 5;
    int i0 = blockIdx.x * 32, j0 = blockIdx.y * 32;
#pragma unroll
    for (int u = 0; u < 4; u++) tile[ty + u * 8][tx] = A[(long)(j0 + ty + u * 8) * 256 + i0 + tx];
    __syncthreads();
#pragma unroll
    for (int u = 0; u < 4; u++) Z[(long)(i0 + ty + u * 8) * 256 + j0 + tx] = f2bf(tile[tx][ty + u * 8] * s);
}

__global__ __launch_bounds__(256)
void k_a3v_merge(const float* __restrict__ pacc, const float* __restrict__ pml,
                 float* __restrict__ t1)
{
    int d = blockIdx.x, h = blockIdx.y, i = threadIdx.x;
    float M = -INFINITY, L = 0.f, num = 0.f;
    for (int c = 0; c < 60; c++) {
        float mc = pml[(long)(h * 60 + c) * 2 * 256 + i];
        float lc = pml[((long)(h * 60 + c) * 2 + 1) * 256 + i];
        float ac = pacc[((long)(h * 60 + c) * 64 + d) * 256 + i];
        if (mc > M) {
            float f = __expf(M - mc);
            num = num * f + ac; L = L * f + lc; M = mc;
        } else {
            float p = __expf(mc - M);
            num = fmaf(p, ac, num); L = fmaf(p, lc, L);
        }
    }
    t1[((long)h * 256 + i) * 64 + d] = num / L;
}

__global__ __launch_bounds__(256)
void k_cls(const ushort* __restrict__ qb, const float* __restrict__ klT,
           const float* __restrict__ Bm, const ushort* __restrict__ vb,
           const float* __restrict__ rw, float* __restrict__ oh)
{
    int h = blockIdx.x, t = threadIdx.x, wid = t >> 6, lane = t & 63;
    __shared__ float qs[64], p[256], red[256];
    __shared__ float rm[4], rsum[4], fin[2];
    if (t < 64) qs[t] = bf2f(qb[((long)h * NPQ + 230) * 64 + t]);
    __syncthreads();
    float s = 0.f;
    for (int d = 0; d < 64; d++) s = fmaf(qs[d], klT[((long)h * 64 + d) * 256 + t], s);
    float m = s;
#pragma unroll
    for (int o = 32; o > 0; o >>= 1) m = fmaxf(m, __shfl_down(m, o));
    if (lane == 0) rm[wid] = m;
    __syncthreads();
    if (t == 0) fin[0] = fmaxf(fmaxf(rm[0], rm[1]), fmaxf(rm[2], rm[3]));
    __syncthreads();
    float e = __expf(s - fin[0]);
    float ss = e;
#pragma unroll
    for (int o = 32; o > 0; o >>= 1) ss += __shfl_down(ss, o);
    if (lane == 0) rsum[wid] = ss;
    __syncthreads();
    if (t == 0) fin[1] = rsum[0] + rsum[1] + rsum[2] + rsum[3];
    __syncthreads();
    p[t] = e / fin[1];
    __syncthreads();
    int d = t & 63, grp = t >> 6;
    float o = 0.f;
    for (int j = grp * 64; j < grp * 64 + 64; j++) o = fmaf(p[j], Bm[((long)h * 256 + j) * 64 + d], o);
    red[t] = o;
    __syncthreads();
    if (t < 64) {
        float val = red[t] + red[t + 64] + red[t + 128] + red[t + 192];
#pragma unroll
        for (int kk = 0; kk < 33; kk++)
            val = fmaf(rw[h * 33 + kk], bf2f(vb[((long)h * NPQ + 214 + kk) * 64 + t]), val);
        oh[h * 64 + t] = val;
    }
}

__global__ __launch_bounds__(256)
void k_copy4(const float4* __restrict__ src, float4* __restrict__ dst, long n4)
{
    long i = (long)blockIdx.x * 256 + threadIdx.x;
    if (i < n4) dst[i] = src[i];
}

// ---------------- combine w7+w5+w3+identity into wc[49][512], bc = b7+b5+b3
__global__ __launch_bounds__(512)
void k_wcomb(const float* __restrict__ w7, const float* __restrict__ b7,
             const float* __restrict__ w5, const float* __restrict__ b5,
             const float* __restrict__ w3, const float* __restrict__ b3,
             float* __restrict__ wc, float* __restrict__ bc)
{
    int k = blockIdx.x, c = threadIdx.x;
    int kr = k / 7, kc = k % 7;
    float v = w7[c * 49 + k];
    if (kr >= 1 && kr <= 5 && kc >= 1 && kc <= 5) v += w5[c * 25 + (kr - 1) * 5 + (kc - 1)];
    if (kr >= 2 && kr <= 4 && kc >= 2 && kc <= 4) v += w3[c * 9 + (kr - 2) * 3 + (kc - 2)];
    if (k == 24) v += 1.f;
    wc[k * 512 + c] = v;
    if (k == 0) bc[c] = b7[c] + b5[c] + b3[c];
}

// ---------------- PPEG v4: async DMA staging (global_load_lds w=16), (256,4).
__global__ __launch_bounds__(256, 4)
void k_ppeg4(const float* __restrict__ cnn, float* __restrict__ hbuf,
             const float* __restrict__ wc, const float* __restrict__ bc)
{
    __shared__ __attribute__((aligned(16))) float tile[320 * 32];
    const int t = threadIdx.x;
    const int w = t >> 6, lane = t & 63;
    const int c0 = blockIdx.x * 16;
    const int r0 = blockIdx.y * 8;
    const int cb = blockIdx.z * 32;
    {
        const int pl = lane >> 3;
        const int c4 = (lane & 7) * 4;
#pragma unroll
        for (int it = 0; it < 10; ++it) {
            int chunk = w * 10 + it;
            int pos = chunk * 8 + pl;
            int pr = pos / 22, pc = pos - pr * 22;
            int gr = r0 + pr - 3, gc = c0 + pc - 3;
            int grc = min(max(gr, 0), HG - 1), gcc = min(max(gc, 0), HG - 1);
            const float* src = cnn + (long)(grc * HG + gcc) * 512 + cb + c4;
            __builtin_amdgcn_global_load_lds(
                (const __attribute__((address_space(1))) void*)src,
                (__attribute__((address_space(3))) void*)(tile + chunk * 256),
                16, 0, 0);
        }
    }
    __syncthreads();
    const bool boundary = (r0 < 3) | (r0 > HG - 11) | (c0 < 3) | (c0 > HG - 19);
    if (boundary) {
        for (int pos = t; pos < 308; pos += 256) {
            int pr = pos / 22, pc = pos - pr * 22;
            int gr = r0 + pr - 3, gc = c0 + pc - 3;
            if (gr < 0 || gr >= HG || gc < 0 || gc >= HG) {
                float4 z = make_float4(0.f, 0.f, 0.f, 0.f);
#pragma unroll
                for (int c4 = 0; c4 < 32; c4 += 4) *(float4*)&tile[pos * 32 + c4] = z;
            }
        }
        __syncthreads();
    }
    const int cp = t & 15;
    const int slot = t >> 4;
    const int orow = slot >> 1;
    const int ohalf = (slot & 1) * 8;
    float a0[8], a1[8];
#pragma unroll
    for (int i = 0; i < 8; i++) { a0[i] = 0.f; a1[i] = 0.f; }
    for (int kr = 0; kr < 7; kr++) {
        float w0[14], w1[14];
        const float* trow = tile + ((orow + kr) * 22 + ohalf) * 32 + cp * 2;
#pragma unroll
        for (int j = 0; j < 14; j++) {
            float2 v = *(const float2*)(trow + j * 32);
            w0[j] = v.x; w1[j] = v.y;
        }
#pragma unroll
        for (int kc = 0; kc < 7; kc++) {
            float2 wv = *(const float2*)(wc + (long)(kr * 7 + kc) * 512 + cb + cp * 2);
#pragma unroll
            for (int i = 0; i < 8; i++) {
                a0[i] = fmaf(wv.x, w0[i + kc], a0[i]);
                a1[i] = fmaf(wv.y, w1[i + kc], a1[i]);
            }
        }
    }
    const float2 bv = *(const float2*)(bc + cb + cp * 2);
    const int gr = r0 + orow;
    if (gr < HG) {
#pragma unroll
        for (int i = 0; i < 8; i++) {
            int gc = c0 + ohalf + i;
            if (gc < HG) {
                float* dst = hbuf + (long)(1 + gr * HG + gc) * 512 + cb + cp * 2;
                dst[0] = a0[i] + bv.x;
                dst[1] = a1[i] + bv.y;
            }
        }
    }
}

__global__ __launch_bounds__(256)
void k_final(const float* __restrict__ hbuf, const float* __restrict__ g,
             const float* __restrict__ b, const float* __restrict__ W2,
             const float* __restrict__ b2, float* __restrict__ out)
{
    __shared__ float y[512];
    __shared__ float rs[4], rq[4], st[2], lg[8];
    int t = threadIdx.x, wid = t >> 6, lane = t & 63;
    float x1 = hbuf[t], x2 = hbuf[t + 256];
    float s = x1 + x2, q = x1 * x1 + x2 * x2;
#pragma unroll
    for (int o = 32; o > 0; o >>= 1) { s += __shfl_down(s, o); q += __shfl_down(q, o); }
    if (lane == 0) { rs[wid] = s; rq[wid] = q; }
    __syncthreads();
    if (t == 0) {
        float S = rs[0] + rs[1] + rs[2] + rs[3];
        float Q = rq[0] + rq[1] + rq[2] + rq[3];
        float mean = S / 512.f;
        float var = Q / 512.f - mean * mean;
        st[0] = mean; st[1] = rsqrtf(var + 1e-5f);
    }
    __syncthreads();
    float mean = st[0], rstd = st[1];
    y[t] = (x1 - mean) * rstd * g[t] + b[t];
    y[t + 256] = (x2 - mean) * rstd * g[t + 256] + b[t + 256];
    __syncthreads();
    if (t < 5) {
        float acc = b2[t];
        for (int kx = 0; kx < 512; kx++) acc = fmaf(y[kx], W2[kx * 5 + t], acc);
        lg[t] = acc;
    }
    __syncthreads();
    if (t == 0) {
        float mx = lg[0]; int am = 0;
        for (int j = 1; j < 5; j++) if (lg[j] > mx) { mx = lg[j]; am = j; }
        float e[5], se = 0.f;
        for (int j = 0; j < 5; j++) { e[j] = __expf(lg[j] - mx); se += e[j]; }
        for (int j = 0; j < 5; j++) { out[j] = lg[j]; out[5 + j] = e[j] / se; }
        out[10] = (float)am;
    }
}

extern "C" void kernel_launch(void* const* d_in, const int* in_sizes, int n_in,
                              void* d_out, int out_size, void* d_ws, size_t ws_size,
                              hipStream_t stream)
{
    const float* data  = (const float*)d_in[0];
    const float* Wfc1  = (const float*)d_in[1];
    const float* bfc1  = (const float*)d_in[2];
    const float* cls   = (const float*)d_in[3];
    const float* ln1g  = (const float*)d_in[4];
    const float* ln1b  = (const float*)d_in[5];
    const float* qkv1  = (const float*)d_in[6];
    const float* out1w = (const float*)d_in[7];
    const float* out1b = (const float*)d_in[8];
    const float* res1  = (const float*)d_in[9];
    const float* w7    = (const float*)d_in[10];
    const float* b7    = (const float*)d_in[11];
    const float* w5    = (const float*)d_in[12];
    const float* b5    = (const float*)d_in[13];
    const float* w3    = (const float*)d_in[14];
    const float* b3    = (const float*)d_in[15];
    const float* ln2g  = (const float*)d_in[16];
    const float* ln2b  = (const float*)d_in[17];
    const float* qkv2  = (const float*)d_in[18];
    const float* out2w = (const float*)d_in[19];
    const float* out2b = (const float*)d_in[20];
    const float* res2  = (const float*)d_in[21];
    const float* normg = (const float*)d_in[22];
    const float* normb = (const float*)d_in[23];
    const float* Wfc2  = (const float*)d_in[24];
    const float* bfc2  = (const float*)d_in[25];
    float* out = (float*)d_out;

    float* W = (float*)d_ws;
    size_t off = 0;
    auto alloc = [&](size_t n) { size_t o = off; off += (n + 255) & ~(size_t)255; return o; };
    float*  hbuf   = W + alloc((size_t)NTOK * 512);
    float*  ohreg  = W + alloc((size_t)15232 * 512);
    float*  oh     = ohreg;
    ushort* xln    = (ushort*)ohreg;
    ushort* qb16   = (ushort*)(W + alloc((size_t)8 * NPQ * 32));
    ushort* kb16   = (ushort*)(W + alloc((size_t)8 * NPQ * 32));
    ushort* vb16   = (ushort*)(W + alloc((size_t)8 * NPQ * 32));
    float*  ql     = W + alloc(8 * 256 * 64);
    ushort* qlb    = (ushort*)(W + alloc(8 * 256 * 32));
    float*  klT    = W + alloc(8 * 64 * 256);
    ushort* klb    = (ushort*)(W + alloc(8 * 256 * 32));
    float*  a2     = W + alloc(8 * 65536);
    ushort* a2b    = (ushort*)(W + alloc(8 * 32768));
    ushort* zb0    = (ushort*)(W + alloc(8 * 32768));
    ushort* zb1    = (ushort*)(W + alloc(8 * 32768));
    ushort* m1b    = (ushort*)(W + alloc(8 * 32768));
    ushort* mab    = (ushort*)(W + alloc(8 * 32768));
    ushort* mbb    = (ushort*)(W + alloc(8 * 32768));
    float*  z0     = W + alloc(8 * 65536);
    float*  t1     = W + alloc(8 * 256 * 64);
    float*  Bm     = W + alloc(8 * 256 * 64);
    ushort* BmbT   = (ushort*)(W + alloc(8 * 256 * 32));   // bf16 BmT [h][64][256]
    float*  scal   = W + alloc(64);
    ushort* ohb16  = (ushort*)(W + alloc((size_t)15232 * 256));
    ushort* WfcT   = (ushort*)(W + alloc(1024 * 256));
    ushort* qkv1T  = (ushort*)(W + alloc(1536 * 256));
    ushort* qkv2T  = (ushort*)(W + alloc(1536 * 256));
    ushort* out1T  = (ushort*)(W + alloc(512 * 256));
    ushort* out2T  = (ushort*)(W + alloc(512 * 256));
    float*  wc     = W + alloc(49 * 512);
    float*  bc     = W + alloc(512);
    float*  big    = W + alloc(8110080);   // pacc+pml | ppeg cnn
    float*  pacc   = big;
    float*  pml    = big + 7864320;
    float*  cnn    = big;
    (void)z0;
    if (ws_size < off * sizeof(float)) return;

    k_wT<<<dim3(16, 32, 1), 256, 0, stream>>>(Wfc1, WfcT, 1024, 512, 0, 0);
    k_wT<<<dim3(48, 16, 1), 256, 0, stream>>>(qkv1, qkv1T, 512, 1536, 0, 0);
    k_wT<<<dim3(48, 16, 1), 256, 0, stream>>>(qkv2, qkv2T, 512, 1536, 0, 0);
    k_wT<<<dim3(16, 16, 1), 256, 0, stream>>>(out1w, out1T, 512, 512, 0, 0);
    k_wT<<<dim3(16, 16, 1), 256, 0, stream>>>(out2w, out2T, 512, 512, 0, 0);
    k_wcomb<<<49, 512, 0, stream>>>(w7, b7, w5, b5, w3, b3, wc, bc);
    // fc1 GEMM with fused fp32->bf16 conversion, depth-2 prefetch ring
    gemm_fc1<<<dim3(4, 235, 1), 256, 0, stream>>>(data, WfcT, hbuf + 512, bfc1);
    k_padcls<<<130, 256, 0, stream>>>(hbuf, cls);

    auto layer = [&](const float* lng, const float* lnb, const ushort* qkvT,
                     const float* outW, const ushort* outT, const float* outB,
                     const float* resW, bool full) {
        k_layernorm<<<NP, 256, 0, stream>>>(hbuf, xln, lng, lnb, 230);
        gemm_qkv_mfma<<<dim3(12, 120, 1), 256, 0, stream>>>(xln, qkvT, qb16, kb16, vb16);
        k_landmarks<<<dim3(256, 8), 64, 0, stream>>>(qb16, kb16, ql, qlb, klT, klb, (unsigned*)scal);
        gemm_f32<<<dim3(4, 4, 8), 256, 0, stream>>>(ql, 64, 16384, klT, 256, 16384,
            a2, 256, 65536, 256, 256, 64, nullptr, nullptr, 0, 0, 0.f, 1.f, 0, 0);
        k_softmax256<<<dim3(256, 8), 256, 0, stream>>>(a2, a2b, 65536);
        k_colmax<<<8, 256, 0, stream>>>(a2, (unsigned*)scal);
        k_zinit<<<dim3(8, 8, 8), 256, 0, stream>>>(a2, zb0, (const unsigned*)scal);
        // pinv: all 6 iterations bf16 MFMA (prefetch + swizzled B^T staging)
        ushort* zbi = zb0; ushort* zbo = zb1;
        for (int it = 0; it < 6; ++it) {
            gemm_nn16<<<dim3(4, 4, 8), 256, 0, stream>>>(a2b, zbi, nullptr, m1b, 256, 256, 1.f, 0.f, 65536);
            gemm_nn16<<<dim3(4, 4, 8), 256, 0, stream>>>(m1b, m1b, m1b, mab, 256, 256, -1.f, 7.f, 65536);
            gemm_nn16<<<dim3(4, 4, 8), 256, 0, stream>>>(m1b, mab, m1b, mbb, 256, 256, -1.f, 15.f, 65536);
            gemm_nn16<<<dim3(4, 4, 8), 256, 0, stream>>>(zbi, mbb, zbi, zbo, 256, 256, -0.25f, 3.25f, 65536);
            ushort* tmp = zbi; zbi = zbo; zbo = tmp;
        }
        k_flash_a3v<<<dim3(60, 2, 8), 256, 0, stream>>>(qlb, kb16, vb16, pacc, pml);
        k_a3v_merge<<<dim3(64, 8), 256, 0, stream>>>(pacc, pml, t1);
        // Bm = z(bf16) @ t1 directly
        gemm_zb<<<dim3(1, 4, 8), 256, 0, stream>>>(zbi, t1, Bm);
        if (full) {
            k_wT<<<dim3(2, 8, 8), 256, 0, stream>>>(Bm, BmbT, 256, 64, 16384, 16384);
            k_attn1<<<dim3(119, 8), 256, 0, stream>>>(qb16, klb, BmbT, vb16, resW, ohb16);
            gemm_mfma<2, 4, 2, 2><<<dim3(4, 237, 1), 256, 0, stream>>>(
                ohb16, 512, 0, outT, 512, 0, hbuf, 512, 0, NTOK, 512, outB, 0, 1);
        } else {
            k_cls<<<8, 256, 0, stream>>>(qb16, klT, Bm, vb16, resW, oh);
            gemm_f32<<<dim3(8, 1, 1), 256, 0, stream>>>(oh, 512, 0, outW, 512, 0,
                hbuf, 512, 0, 1, 512, 512, outB, nullptr, 0, 0, 0.f, 1.f, 0, 1);
        }
    };

    layer(ln1g, ln1b, qkv1T, out1w, out1T, out1b, res1, true);
    k_copy4<<<(1936512 + 255) / 256, 256, 0, stream>>>((const float4*)(hbuf + 512), (float4*)cnn, 1936512);
    k_ppeg4<<<dim3(8, 16, 16), 256, 0, stream>>>(cnn, hbuf, wc, bc);
    layer(ln2g, ln2b, qkv2T, out2w, out2T, out2b, res2, false);
    k_final<<<1, 256, 0, stream>>>(hbuf, normg, normb, Wfc2, bfc2, out);
}

// Round 15
// 1024.901 us; speedup vs baseline: 1.8181x; 1.8181x over previous
//
#include <hip/hip_runtime.h>
#include <math.h>

#define NP 15360
#define NPQ 15488
#define NTOK 15130
#define HG 123

typedef __attribute__((ext_vector_type(8))) short s8b;
typedef __attribute__((ext_vector_type(4))) float f4;

__device__ inline float bf2f(ushort u) { return __uint_as_float(((unsigned)u) << 16); }
__device__ inline ushort f2bf(float f) {
    unsigned u = __float_as_uint(f);
    unsigned r = (u + 0x7fffu + ((u >> 16) & 1u)) >> 16;
    return (ushort)r;
}

// ---------------- generic fp32 GEMM (small/sensitive ops): C = cS*(A@B) + eS*E + bias
__global__ __launch_bounds__(256)
void gemm_f32(const float* __restrict__ A, int lda, long sA,
              const float* __restrict__ B, int ldb, long sB,
              float* __restrict__ C, int ldc, long sC,
              int M, int N, int K,
              const float* __restrict__ bias,
              const float* __restrict__ E, int ldE, long sE, float eS,
              float cS, int relu, int accum)
{
    A += (long)blockIdx.z * sA;
    B += (long)blockIdx.z * sB;
    C += (long)blockIdx.z * sC;
    if (E) E += (long)blockIdx.z * sE;
    const int m0 = blockIdx.y * 64, n0 = blockIdx.x * 64;
    const int t = threadIdx.x;
    const int tx = t & 15, ty = t >> 4;
    __shared__ float As[16][64];
    __shared__ float Bs[16][64];
    float acc[4][4] = {};
    const int arow = t >> 2, akc = (t & 3) * 4;
    const int brow = t >> 4, bnc = (t & 15) * 4;
    for (int k0 = 0; k0 < K; k0 += 16) {
        float4 av = make_float4(0.f, 0.f, 0.f, 0.f);
        if (m0 + arow < M) av = *(const float4*)(A + (long)(m0 + arow) * lda + k0 + akc);
        As[akc + 0][arow] = av.x; As[akc + 1][arow] = av.y;
        As[akc + 2][arow] = av.z; As[akc + 3][arow] = av.w;
        float4 bv = *(const float4*)(B + (long)(k0 + brow) * ldb + n0 + bnc);
        *(float4*)&Bs[brow][bnc] = bv;
        __syncthreads();
#pragma unroll
        for (int kk = 0; kk < 16; ++kk) {
            float4 a4 = *(const float4*)&As[kk][ty * 4];
            float4 b4 = *(const float4*)&Bs[kk][tx * 4];
            float a[4] = {a4.x, a4.y, a4.z, a4.w};
            float b[4] = {b4.x, b4.y, b4.z, b4.w};
#pragma unroll
            for (int i = 0; i < 4; i++)
#pragma unroll
                for (int j = 0; j < 4; j++) acc[i][j] = fmaf(a[i], b[j], acc[i][j]);
        }
        __syncthreads();
    }
#pragma unroll
    for (int i = 0; i < 4; i++) {
        int m = m0 + ty * 4 + i;
        if (m < M) {
#pragma unroll
            for (int j = 0; j < 4; j++) {
                int n = n0 + tx * 4 + j;
                float v = cS * acc[i][j];
                if (E) v = fmaf(eS, E[(long)m * ldE + n], v);
                if (bias) v += bias[n];
                if (relu) v = fmaxf(v, 0.f);
                if (accum) C[(long)m * ldc + n] += v;
                else C[(long)m * ldc + n] = v;
            }
        }
    }
}

// ---------------- Bm GEMM: C(f32,[256][64]) = A(bf16,[256][256]) @ B(f32,[256][64]).
__global__ __launch_bounds__(256)
void gemm_zb(const ushort* __restrict__ A, const float* __restrict__ B,
             float* __restrict__ C)
{
    A += (long)blockIdx.z * 65536;
    B += (long)blockIdx.z * 16384;
    C += (long)blockIdx.z * 16384;
    const int m0 = blockIdx.y * 64;
    const int t = threadIdx.x;
    const int tx = t & 15, ty = t >> 4;
    __shared__ float As[16][64];
    __shared__ float Bs[16][64];
    float acc[4][4] = {};
    const int arow = t >> 2, akc = (t & 3) * 4;
    const int brow = t >> 4, bnc = (t & 15) * 4;
    for (int k0 = 0; k0 < 256; k0 += 16) {
        ushort4 av = *(const ushort4*)(A + (long)(m0 + arow) * 256 + k0 + akc);
        As[akc + 0][arow] = bf2f(av.x); As[akc + 1][arow] = bf2f(av.y);
        As[akc + 2][arow] = bf2f(av.z); As[akc + 3][arow] = bf2f(av.w);
        float4 bv = *(const float4*)(B + (long)(k0 + brow) * 64 + bnc);
        *(float4*)&Bs[brow][bnc] = bv;
        __syncthreads();
#pragma unroll
        for (int kk = 0; kk < 16; ++kk) {
            float4 a4 = *(const float4*)&As[kk][ty * 4];
            float4 b4 = *(const float4*)&Bs[kk][tx * 4];
            float a[4] = {a4.x, a4.y, a4.z, a4.w};
            float b[4] = {b4.x, b4.y, b4.z, b4.w};
#pragma unroll
            for (int i = 0; i < 4; i++)
#pragma unroll
                for (int j = 0; j < 4; j++) acc[i][j] = fmaf(a[i], b[j], acc[i][j]);
        }
        __syncthreads();
    }
#pragma unroll
    for (int i = 0; i < 4; i++) {
        int m = m0 + ty * 4 + i;
#pragma unroll
        for (int j = 0; j < 4; j++) {
            int n = tx * 4 + j;
            C[(long)m * 64 + n] = acc[i][j];
        }
    }
}

// ---------------- bf16 MFMA GEMM: C(fp32) = A(bf16,[M][K]) @ Bt(bf16,[N][K])^T
// v2: register prefetch of next K-tile, bijective XCD swizzle, TM=64 tiles.
template<int MT, int NT, int WROWS, int WCOLS>
__global__ __launch_bounds__(256)
void gemm_mfma(const ushort* __restrict__ A, int lda, long sA,
               const ushort* __restrict__ Bt, int ldb, long sB,
               float* __restrict__ C, int ldc, long sC,
               int M, int K,
               const float* __restrict__ bias, int relu, int accum)
{
    constexpr int TM = MT * 16 * WROWS;
    constexpr int TN = NT * 16 * WCOLS;
    constexpr int BKP = 40;
    constexpr int AIT = TM / 64;
    constexpr int BIT = TN / 64;
    __shared__ ushort As[TM * BKP];
    __shared__ ushort Bs[TN * BKP];
    A  += (long)blockIdx.z * sA;
    Bt += (long)blockIdx.z * sB;
    C  += (long)blockIdx.z * sC;
    const int t = threadIdx.x;
    const int nwg = gridDim.x * gridDim.y;
    const int flat = blockIdx.y * gridDim.x + blockIdx.x;
    const int q8 = nwg >> 3, r8 = nwg & 7;
    const int xcd = flat & 7, idx = flat >> 3;
    const int swz = (xcd < r8) ? (xcd * (q8 + 1) + idx)
                               : (r8 * (q8 + 1) + (xcd - r8) * q8 + idx);
    const int m0 = (swz / gridDim.x) * TM;
    const int n0 = (swz % gridDim.x) * TN;
    const int w = t >> 6, l = t & 63;
    const int wm = (w / WCOLS) * (MT * 16), wn = (w % WCOLS) * (NT * 16);
    const int lr = l & 15;
    const int lk = (l >> 4) * 8;
    const int srow = t >> 2, skc = (t & 3) * 8;
    f4 acc[MT][NT] = {};
    s8b pa[AIT], pb[BIT];
#pragma unroll
    for (int i = 0; i < AIT; i++)
        pa[i] = *(const s8b*)(A + (long)(m0 + srow + i * 64) * lda + skc);
#pragma unroll
    for (int i = 0; i < BIT; i++)
        pb[i] = *(const s8b*)(Bt + (long)(n0 + srow + i * 64) * ldb + skc);
    for (int k0 = 0; k0 < K; k0 += 32) {
        __syncthreads();
#pragma unroll
        for (int i = 0; i < AIT; i++)
            *(s8b*)(&As[(srow + i * 64) * BKP + skc]) = pa[i];
#pragma unroll
        for (int i = 0; i < BIT; i++)
            *(s8b*)(&Bs[(srow + i * 64) * BKP + skc]) = pb[i];
        if (k0 + 32 < K) {
#pragma unroll
            for (int i = 0; i < AIT; i++)
                pa[i] = *(const s8b*)(A + (long)(m0 + srow + i * 64) * lda + k0 + 32 + skc);
#pragma unroll
            for (int i = 0; i < BIT; i++)
                pb[i] = *(const s8b*)(Bt + (long)(n0 + srow + i * 64) * ldb + k0 + 32 + skc);
        }
        __syncthreads();
        s8b af[MT], bf[NT];
#pragma unroll
        for (int i = 0; i < MT; i++) af[i] = *(const s8b*)(&As[(wm + i * 16 + lr) * BKP + lk]);
#pragma unroll
        for (int j = 0; j < NT; j++) bf[j] = *(const s8b*)(&Bs[(wn + j * 16 + lr) * BKP + lk]);
#pragma unroll
        for (int i = 0; i < MT; i++)
#pragma unroll
            for (int j = 0; j < NT; j++)
                acc[i][j] = __builtin_amdgcn_mfma_f32_16x16x32_bf16(af[i], bf[j], acc[i][j], 0, 0, 0);
    }
    const int orow = (l >> 4) * 4;
#pragma unroll
    for (int i = 0; i < MT; i++) {
#pragma unroll
        for (int r = 0; r < 4; r++) {
            int m = m0 + wm + i * 16 + orow + r;
            if (m < M) {
#pragma unroll
                for (int j = 0; j < NT; j++) {
                    int n = n0 + wn + j * 16 + lr;
                    float vv = acc[i][j][r];
                    if (bias) vv += bias[n];
                    if (relu) vv = fmaxf(vv, 0.f);
                    if (accum) C[(long)m * ldc + n] += vv;
                    else C[(long)m * ldc + n] = vv;
                }
            }
        }
    }
}

// ---------------- fc1 GEMM with fused fp32->bf16 A conversion.
// v3: depth-2 prefetch with STATIC slot names (pa0/pb0 even steps, pa1/pb1 odd) —
// v2's runtime-indexed ring went to scratch (VGPR 56, 913us, rule: runtime-indexed
// ext_vector arrays spill). K-loop unrolled x2 so every access is compile-time.
// LDS contents & MFMA order bit-identical to v1/v2.
__global__ __launch_bounds__(256)
void gemm_fc1(const float* __restrict__ A, const ushort* __restrict__ Bt,
              float* __restrict__ C, const float* __restrict__ bias)
{
    constexpr int BKP = 40;
    __shared__ ushort As[64 * BKP];
    __shared__ ushort Bs[128 * BKP];
    const int t = threadIdx.x;
    const int nwg = gridDim.x * gridDim.y;
    const int flat = blockIdx.y * gridDim.x + blockIdx.x;
    const int q8 = nwg >> 3, r8 = nwg & 7;
    const int xcd = flat & 7, idx = flat >> 3;
    const int swz = (xcd < r8) ? (xcd * (q8 + 1) + idx)
                               : (r8 * (q8 + 1) + (xcd - r8) * q8 + idx);
    const int m0 = (swz / gridDim.x) * 64;
    const int n0 = (swz % gridDim.x) * 128;
    const int w = t >> 6, l = t & 63;
    const int wm = (w >> 1) * 32, wn = (w & 1) * 64;
    const int lr = l & 15, lk = (l >> 4) * 8;
    const int srow = t >> 2, skc = (t & 3) * 8;
    int ar = m0 + srow; if (ar > 14999) ar = 14999;
    const float* arow_p = A + (long)ar * 1024;
    const ushort* b0p = Bt + (long)(n0 + srow) * 1024;
    const ushort* b1p = Bt + (long)(n0 + srow + 64) * 1024;
    f4 acc[2][4] = {};
    auto cvt8 = [&](const float* p) {
        float4 v0 = *(const float4*)p;
        float4 v1 = *(const float4*)(p + 4);
        s8b r;
        ((ushort*)&r)[0] = f2bf(v0.x); ((ushort*)&r)[1] = f2bf(v0.y);
        ((ushort*)&r)[2] = f2bf(v0.z); ((ushort*)&r)[3] = f2bf(v0.w);
        ((ushort*)&r)[4] = f2bf(v1.x); ((ushort*)&r)[5] = f2bf(v1.y);
        ((ushort*)&r)[6] = f2bf(v1.z); ((ushort*)&r)[7] = f2bf(v1.w);
        return r;
    };
    // depth-2 prefetch, static names: slot0 = even k-steps, slot1 = odd k-steps
    s8b pa0 = cvt8(arow_p + skc);
    s8b pa1 = cvt8(arow_p + 32 + skc);
    s8b pb00 = *(const s8b*)(b0p + skc);
    s8b pb01 = *(const s8b*)(b1p + skc);
    s8b pb10 = *(const s8b*)(b0p + 32 + skc);
    s8b pb11 = *(const s8b*)(b1p + 32 + skc);
    for (int k0 = 0; k0 < 1024; k0 += 64) {
        // ---- even step (uses slot0), refills slot0 for k0+64
        __syncthreads();
        *(s8b*)(&As[srow * BKP + skc]) = pa0;
        *(s8b*)(&Bs[srow * BKP + skc]) = pb00;
        *(s8b*)(&Bs[(srow + 64) * BKP + skc]) = pb01;
        if (k0 + 64 < 1024) {
            pa0 = cvt8(arow_p + k0 + 64 + skc);
            pb00 = *(const s8b*)(b0p + k0 + 64 + skc);
            pb01 = *(const s8b*)(b1p + k0 + 64 + skc);
        }
        __syncthreads();
        {
            s8b af[2], bf[4];
#pragma unroll
            for (int i = 0; i < 2; i++) af[i] = *(const s8b*)(&As[(wm + i * 16 + lr) * BKP + lk]);
#pragma unroll
            for (int j = 0; j < 4; j++) bf[j] = *(const s8b*)(&Bs[(wn + j * 16 + lr) * BKP + lk]);
#pragma unroll
            for (int i = 0; i < 2; i++)
#pragma unroll
                for (int j = 0; j < 4; j++)
                    acc[i][j] = __builtin_amdgcn_mfma_f32_16x16x32_bf16(af[i], bf[j], acc[i][j], 0, 0, 0);
        }
        // ---- odd step (uses slot1), refills slot1 for k0+96
        __syncthreads();
        *(s8b*)(&As[srow * BKP + skc]) = pa1;
        *(s8b*)(&Bs[srow * BKP + skc]) = pb10;
        *(s8b*)(&Bs[(srow + 64) * BKP + skc]) = pb11;
        if (k0 + 96 < 1024) {
            pa1 = cvt8(arow_p + k0 + 96 + skc);
            pb10 = *(const s8b*)(b0p + k0 + 96 + skc);
            pb11 = *(const s8b*)(b1p + k0 + 96 + skc);
        }
        __syncthreads();
        {
            s8b af[2], bf[4];
#pragma unroll
            for (int i = 0; i < 2; i++) af[i] = *(const s8b*)(&As[(wm + i * 16 + lr) * BKP + lk]);
#pragma unroll
            for (int j = 0; j < 4; j++) bf[j] = *(const s8b*)(&Bs[(wn + j * 16 + lr) * BKP + lk]);
#pragma unroll
            for (int i = 0; i < 2; i++)
#pragma unroll
                for (int j = 0; j < 4; j++)
                    acc[i][j] = __builtin_amdgcn_mfma_f32_16x16x32_bf16(af[i], bf[j], acc[i][j], 0, 0, 0);
        }
    }
    const int orow = (l >> 4) * 4;
#pragma unroll
    for (int i = 0; i < 2; i++) {
#pragma unroll
        for (int r = 0; r < 4; r++) {
            int m = m0 + wm + i * 16 + orow + r;
            if (m < 15000) {
#pragma unroll
                for (int j = 0; j < 4; j++) {
                    int n = n0 + wn + j * 16 + lr;
                    float vv = acc[i][j][r] + bias[n];
                    vv = fmaxf(vv, 0.f);
                    C[(long)m * 512 + n] = vv;
                }
            }
        }
    }
}

// ---------------- bf16-in/bf16-out MFMA GEMM, B row-major [K][N]: C16 = bf16(cS*(A@B) + eS*E16)
// v2: register prefetch of next K-tile; rotation-swizzled B^T staging.
__global__ __launch_bounds__(256)
void gemm_nn16(const ushort* __restrict__ A, const ushort* __restrict__ B,
               const ushort* __restrict__ E, ushort* __restrict__ C,
               int N, int K, float cS, float eS, long sAB)
{
    __shared__ ushort As[64 * 40];
    __shared__ ushort Bs[64 * 40];
    A += (long)blockIdx.z * sAB;
    B += (long)blockIdx.z * sAB;
    if (E) E += (long)blockIdx.z * sAB;
    C += (long)blockIdx.z * sAB;
    const int t = threadIdx.x;
    const int m0 = blockIdx.y * 64, n0 = blockIdx.x * 64;
    const int w = t >> 6, l = t & 63;
    const int wm = (w >> 1) * 32, wn = (w & 1) * 32;
    const int lr = l & 15, lk = (l >> 4) * 8;
    const int quad = l >> 4;
    const int arow = t >> 2, akc = (t & 3) * 8;
    const int bkk = t >> 3, bnc = (t & 7) * 8;
    const int bcolp = (bkk + ((bnc >> 3) & 3) * 8) & 31;   // rot by (n>>3)&3
    f4 acc[2][2] = {};
    s8b pa = *(const s8b*)(A + (long)(m0 + arow) * K + akc);
    s8b pb = *(const s8b*)(B + (long)bkk * N + n0 + bnc);
    for (int k0 = 0; k0 < K; k0 += 32) {
        __syncthreads();
        *(s8b*)(&As[arow * 40 + akc]) = pa;
#pragma unroll
        for (int j = 0; j < 8; j++) Bs[(bnc + j) * 40 + bcolp] = ((ushort*)&pb)[j];
        if (k0 + 32 < K) {
            pa = *(const s8b*)(A + (long)(m0 + arow) * K + k0 + 32 + akc);
            pb = *(const s8b*)(B + (long)(k0 + 32 + bkk) * N + n0 + bnc);
        }
        __syncthreads();
        s8b af[2], bf[2];
#pragma unroll
        for (int i = 0; i < 2; i++) af[i] = *(const s8b*)(&As[(wm + i * 16 + lr) * 40 + lk]);
#pragma unroll
        for (int j = 0; j < 2; j++) {
            int n = wn + j * 16 + lr;
            int cb = ((quad + ((n >> 3) & 3)) & 3) * 8;
            bf[j] = *(const s8b*)(&Bs[n * 40 + cb]);
        }
#pragma unroll
        for (int i = 0; i < 2; i++)
#pragma unroll
            for (int j = 0; j < 2; j++)
                acc[i][j] = __builtin_amdgcn_mfma_f32_16x16x32_bf16(af[i], bf[j], acc[i][j], 0, 0, 0);
    }
    const int orow = (l >> 4) * 4;
#pragma unroll
    for (int i = 0; i < 2; i++)
#pragma unroll
        for (int r = 0; r < 4; r++) {
            int m = m0 + wm + i * 16 + orow + r;
#pragma unroll
            for (int j = 0; j < 2; j++) {
                int n = wn + j * 16 + lr;
                float vv = cS * acc[i][j][r];
                if (E) vv = fmaf(eS, bf2f(E[(long)m * N + n0 + n]), vv);
                C[(long)m * N + n0 + n] = f2bf(vv);
            }
        }
}

// ---------------- qkv MFMA GEMM, scatter into bf16 q/k/v [head][NPQ][64], q scaled 1/8
// v2: register prefetch of next K-tile + bijective XCD swizzle.
__global__ __launch_bounds__(256)
void gemm_qkv_mfma(const ushort* __restrict__ A, const ushort* __restrict__ Bt,
                   ushort* __restrict__ qo, ushort* __restrict__ ko, ushort* __restrict__ vo)
{
    constexpr int BKP = 40;
    __shared__ ushort As[128 * BKP];
    __shared__ ushort Bs[128 * BKP];
    const int t = threadIdx.x;
    const int nwg = gridDim.x * gridDim.y;
    const int flat = blockIdx.y * gridDim.x + blockIdx.x;
    const int q8 = nwg >> 3, r8 = nwg & 7;
    const int xcd = flat & 7, idx = flat >> 3;
    const int swz = (xcd < r8) ? (xcd * (q8 + 1) + idx)
                               : (r8 * (q8 + 1) + (xcd - r8) * q8 + idx);
    const int m0 = (swz / gridDim.x) * 128;
    const int n0 = (swz % gridDim.x) * 128;
    const int w = t >> 6, l = t & 63;
    const int wm = (w >> 1) * 64, wn = (w & 1) * 64;
    const int lr = l & 15;
    const int lk = (l >> 4) * 8;
    const int srow = t >> 2, skc = (t & 3) * 8;
    f4 acc[4][4] = {};
    s8b pa[2], pb[2];
#pragma unroll
    for (int i = 0; i < 2; i++) {
        pa[i] = *(const s8b*)(A + (long)(m0 + srow + i * 64) * 512 + skc);
        pb[i] = *(const s8b*)(Bt + (long)(n0 + srow + i * 64) * 512 + skc);
    }
    for (int k0 = 0; k0 < 512; k0 += 32) {
        __syncthreads();
#pragma unroll
        for (int i = 0; i < 2; i++) {
            *(s8b*)(&As[(srow + i * 64) * BKP + skc]) = pa[i];
            *(s8b*)(&Bs[(srow + i * 64) * BKP + skc]) = pb[i];
        }
        if (k0 + 32 < 512) {
#pragma unroll
            for (int i = 0; i < 2; i++) {
                pa[i] = *(const s8b*)(A + (long)(m0 + srow + i * 64) * 512 + k0 + 32 + skc);
                pb[i] = *(const s8b*)(Bt + (long)(n0 + srow + i * 64) * 512 + k0 + 32 + skc);
            }
        }
        __syncthreads();
        s8b af[4], bf[4];
#pragma unroll
        for (int i = 0; i < 4; i++) af[i] = *(const s8b*)(&As[(wm + i * 16 + lr) * BKP + lk]);
#pragma unroll
        for (int j = 0; j < 4; j++) bf[j] = *(const s8b*)(&Bs[(wn + j * 16 + lr) * BKP + lk]);
#pragma unroll
        for (int i = 0; i < 4; i++)
#pragma unroll
            for (int j = 0; j < 4; j++)
                acc[i][j] = __builtin_amdgcn_mfma_f32_16x16x32_bf16(af[i], bf[j], acc[i][j], 0, 0, 0);
    }
    const int orow = (l >> 4) * 4;
#pragma unroll
    for (int i = 0; i < 4; i++) {
#pragma unroll
        for (int r = 0; r < 4; r++) {
            int m = m0 + wm + i * 16 + orow + r;
#pragma unroll
            for (int j = 0; j < 4; j++) {
                int col = n0 + wn + j * 16 + lr;
                int which = col >> 9, h = (col >> 6) & 7, d = col & 63;
                float vv = acc[i][j][r];
                if (which == 0) vv *= 0.125f;
                ushort* dst = which == 0 ? qo : (which == 1 ? ko : vo);
                dst[((long)h * NPQ + m) * 64 + d] = f2bf(vv);
            }
        }
    }
}

// ---------------- flash a3@v, MAX-FREE (scores |s|<~1): p=exp(s), lsum via ones-MFMA, no shuffles.
// v2: __launch_bounds__(256,3) for VGPR headroom; register prefetch of next-sub
// V row + K fragments one sub ahead so global latency hides under compute+barriers.
__global__ __launch_bounds__(256, 3)
void k_flash_a3v(const ushort* __restrict__ qlb, const ushort* __restrict__ kg,
                 const ushort* __restrict__ vg,
                 float* __restrict__ pacc, float* __restrict__ pml)
{
    const int c = blockIdx.x;
    const int qt = blockIdx.y;
    const int h = blockIdx.z;
    const int t = threadIdx.x;
    const int w = t >> 6, lane = t & 63;
    const int quad = lane >> 4, l16 = lane & 15;
    const s8b vones = {0x3F80, 0x3F80, 0x3F80, 0x3F80, 0x3F80, 0x3F80, 0x3F80, 0x3F80};

    __shared__ union {
        struct { ushort Vt[64][40]; ushort Ps[128][40]; } s;
        float Os[128][68];
    } L;

    s8b aq[2][2];
    const ushort* qbase = qlb + ((long)h * 256 + qt * 128 + w * 32) * 64;
#pragma unroll
    for (int mi = 0; mi < 2; mi++)
#pragma unroll
        for (int kf = 0; kf < 2; kf++)
            aq[mi][kf] = *(const s8b*)(qbase + (mi * 16 + l16) * 64 + kf * 32 + quad * 8);

    f4 oacc[2][4] = {};
    f4 lacc[2] = {};

    const ushort* kh = kg + (long)h * NPQ * 64;
    const ushort* vh = vg + (long)h * NPQ * 64;
    const int key0c = c * 256;

    const int vkk = (t >> 3) & 31;
    const int vdc = (t & 7) * 8;
    const int vcolp = (vkk + ((vdc >> 3) & 3) * 8) & 31;

    s8b vvN = *(const s8b*)(vh + (long)(key0c + vkk) * 64 + vdc);
    s8b bqN[2][2];
#pragma unroll
    for (int nj = 0; nj < 2; nj++)
#pragma unroll
        for (int kf = 0; kf < 2; kf++)
            bqN[nj][kf] = *(const s8b*)(kh + (long)(key0c + nj * 16 + l16) * 64 + kf * 32 + quad * 8);

#pragma unroll
    for (int sub = 0; sub < 8; sub++) {
        int key0 = key0c + sub * 32;
        s8b vvC = vvN;
        s8b bq[2][2];
#pragma unroll
        for (int nj = 0; nj < 2; nj++)
#pragma unroll
            for (int kf = 0; kf < 2; kf++) bq[nj][kf] = bqN[nj][kf];
        if (sub < 7) {
            vvN = *(const s8b*)(vh + (long)(key0 + 32 + vkk) * 64 + vdc);
#pragma unroll
            for (int nj = 0; nj < 2; nj++)
#pragma unroll
                for (int kf = 0; kf < 2; kf++)
                    bqN[nj][kf] = *(const s8b*)(kh + (long)(key0 + 32 + nj * 16 + l16) * 64 + kf * 32 + quad * 8);
        }
        __syncthreads();
        {
#pragma unroll
            for (int j = 0; j < 8; j++) L.s.Vt[vdc + j][vcolp] = ((ushort*)&vvC)[j];
        }
        f4 sacc[2][2] = {};
#pragma unroll
        for (int mi = 0; mi < 2; mi++)
#pragma unroll
            for (int nj = 0; nj < 2; nj++) {
                sacc[mi][nj] = __builtin_amdgcn_mfma_f32_16x16x32_bf16(aq[mi][0], bq[nj][0], sacc[mi][nj], 0, 0, 0);
                sacc[mi][nj] = __builtin_amdgcn_mfma_f32_16x16x32_bf16(aq[mi][1], bq[nj][1], sacc[mi][nj], 0, 0, 0);
            }
#pragma unroll
        for (int mi = 0; mi < 2; mi++)
#pragma unroll
            for (int r = 0; r < 4; r++) {
                int row = w * 32 + mi * 16 + quad * 4 + r;
                L.s.Ps[row][l16]      = f2bf(__expf(sacc[mi][0][r]));
                L.s.Ps[row][16 + l16] = f2bf(__expf(sacc[mi][1][r]));
            }
        __syncthreads();
        s8b ap[2], bv[4];
#pragma unroll
        for (int mi = 0; mi < 2; mi++)
            ap[mi] = *(const s8b*)(&L.s.Ps[w * 32 + mi * 16 + l16][quad * 8]);
#pragma unroll
        for (int dj = 0; dj < 4; dj++) {
            int d = dj * 16 + l16;
            int rot = (d >> 3) & 3;
            int cb = ((quad + rot) & 3) * 8;
            bv[dj] = *(const s8b*)(&L.s.Vt[d][cb]);
        }
#pragma unroll
        for (int mi = 0; mi < 2; mi++) {
#pragma unroll
            for (int dj = 0; dj < 4; dj++)
                oacc[mi][dj] = __builtin_amdgcn_mfma_f32_16x16x32_bf16(ap[mi], bv[dj], oacc[mi][dj], 0, 0, 0);
            lacc[mi] = __builtin_amdgcn_mfma_f32_16x16x32_bf16(ap[mi], vones, lacc[mi], 0, 0, 0);
        }
    }
    __syncthreads();
#pragma unroll
    for (int mi = 0; mi < 2; mi++)
#pragma unroll
        for (int dj = 0; dj < 4; dj++)
#pragma unroll
            for (int r = 0; r < 4; r++)
                L.Os[w * 32 + mi * 16 + quad * 4 + r][dj * 16 + l16] = oacc[mi][dj][r];
    long pbase = (long)(h * 60 + c);
    if (l16 == 0) {
#pragma unroll
        for (int mi = 0; mi < 2; mi++)
#pragma unroll
            for (int r = 0; r < 4; r++) {
                int i = qt * 128 + w * 32 + mi * 16 + quad * 4 + r;
                pml[pbase * 512 + i] = 0.f;
                pml[pbase * 512 + 256 + i] = lacc[mi][r];
            }
    }
    __syncthreads();
    float* pc = pacc + pbase * 16384 + qt * 128;
    int d = t >> 2, ig = t & 3;
#pragma unroll
    for (int u = 0; u < 8; u++) {
        int i0 = ig * 32 + u * 4;
        float4 v4 = make_float4(L.Os[i0][d], L.Os[i0 + 1][d], L.Os[i0 + 2][d], L.Os[i0 + 3][d]);
        *(float4*)(pc + (long)d * 256 + i0) = v4;
    }
}

// ---------------- fused sim1+softmax+@BmT attention + res-conv; MAX-FREE single pass,
// wave-local Ps (no barriers in K-loop), lsum via ones-MFMA (no shuffles).
// v3 (proven 48us): __launch_bounds__(256,3); register dbuf of next-sub K frags;
// bv issued at sub top; conv uses vr[48] register window from LDS.
__global__ __launch_bounds__(256, 3)
void k_attn1(const ushort* __restrict__ qg, const ushort* __restrict__ klb,
             const ushort* __restrict__ BmT, const ushort* __restrict__ vg,
             const float* __restrict__ rw, ushort* __restrict__ ohb)
{
    const int m0 = blockIdx.x * 128;
    const int h = blockIdx.y;
    const int t = threadIdx.x;
    const int w = t >> 6, lane = t & 63;
    const int quad = lane >> 4, l16 = lane & 15;
    const s8b vones = {0x3F80, 0x3F80, 0x3F80, 0x3F80, 0x3F80, 0x3F80, 0x3F80, 0x3F80};

    __shared__ union {
        ushort Ps[2][128][40];
        ushort Os[128][68];
    } L;
    __shared__ __attribute__((aligned(16))) ushort Vs[160][64];  // v rows [214+m0, 214+m0+160)

    const ushort* vh = vg + (long)h * NPQ * 64;
    {
        const ushort* srcw = vh + (long)(214 + m0 + w * 40) * 64 + lane * 8;
        ushort* dstw = &Vs[w * 40][0];
#pragma unroll
        for (int it = 0; it < 5; it++)
            __builtin_amdgcn_global_load_lds(
                (const __attribute__((address_space(1))) void*)(srcw + it * 512),
                (__attribute__((address_space(3))) void*)(dstw + it * 512),
                16, 0, 0);
    }

    s8b aq[2][2];
    const ushort* qbase = qg + ((long)h * NPQ + 230 + m0 + w * 32) * 64;
#pragma unroll
    for (int mi = 0; mi < 2; mi++)
#pragma unroll
        for (int kf = 0; kf < 2; kf++)
            aq[mi][kf] = *(const s8b*)(qbase + (mi * 16 + l16) * 64 + kf * 32 + quad * 8);

    const ushort* kh = klb + (long)h * 16384;
    const ushort* bmt = BmT + (long)h * 16384;

    s8b bqN[2][2];
#pragma unroll
    for (int nj = 0; nj < 2; nj++)
#pragma unroll
        for (int kf = 0; kf < 2; kf++)
            bqN[nj][kf] = *(const s8b*)(kh + (long)(nj * 16 + l16) * 64 + kf * 32 + quad * 8);

    f4 oacc[2][4] = {};
    f4 lacc[2] = {};
#pragma unroll
    for (int sub = 0; sub < 8; sub++) {
        int key0 = sub * 32;
        s8b bq[2][2];
#pragma unroll
        for (int nj = 0; nj < 2; nj++)
#pragma unroll
            for (int kf = 0; kf < 2; kf++) bq[nj][kf] = bqN[nj][kf];
        if (sub < 7) {
#pragma unroll
            for (int nj = 0; nj < 2; nj++)
#pragma unroll
                for (int kf = 0; kf < 2; kf++)
                    bqN[nj][kf] = *(const s8b*)(kh + (long)(key0 + 32 + nj * 16 + l16) * 64 + kf * 32 + quad * 8);
        }
        s8b bv[4];
#pragma unroll
        for (int dj = 0; dj < 4; dj++)
            bv[dj] = *(const s8b*)(bmt + (long)(dj * 16 + l16) * 256 + key0 + quad * 8);
        f4 sacc[2][2] = {};
#pragma unroll
        for (int mi = 0; mi < 2; mi++)
#pragma unroll
            for (int nj = 0; nj < 2; nj++) {
                sacc[mi][nj] = __builtin_amdgcn_mfma_f32_16x16x32_bf16(aq[mi][0], bq[nj][0], sacc[mi][nj], 0, 0, 0);
                sacc[mi][nj] = __builtin_amdgcn_mfma_f32_16x16x32_bf16(aq[mi][1], bq[nj][1], sacc[mi][nj], 0, 0, 0);
            }
        int par = sub & 1;
#pragma unroll
        for (int mi = 0; mi < 2; mi++)
#pragma unroll
            for (int r = 0; r < 4; r++) {
                int row = w * 32 + mi * 16 + quad * 4 + r;
                L.Ps[par][row][l16]      = f2bf(__expf(sacc[mi][0][r]));
                L.Ps[par][row][16 + l16] = f2bf(__expf(sacc[mi][1][r]));
            }
        s8b ap[2];
#pragma unroll
        for (int mi = 0; mi < 2; mi++)
            ap[mi] = *(const s8b*)(&L.Ps[par][w * 32 + mi * 16 + l16][quad * 8]);
#pragma unroll
        for (int mi = 0; mi < 2; mi++) {
#pragma unroll
            for (int dj = 0; dj < 4; dj++)
                oacc[mi][dj] = __builtin_amdgcn_mfma_f32_16x16x32_bf16(ap[mi], bv[dj], oacc[mi][dj], 0, 0, 0);
            lacc[mi] = __builtin_amdgcn_mfma_f32_16x16x32_bf16(ap[mi], vones, lacc[mi], 0, 0, 0);
        }
    }
    __syncthreads();

    if (214 + m0 + 160 > NP) {
        for (int r = w * 32; r < w * 32 + 64 && r < 160; ++r)
            if (214 + m0 + r >= NP) Vs[r][lane] = 0;
    }

#pragma unroll
    for (int mi = 0; mi < 2; mi++)
#pragma unroll
        for (int r = 0; r < 4; r++) {
            float inv = 1.f / lacc[mi][r];
            int row = w * 32 + mi * 16 + quad * 4 + r;
#pragma unroll
            for (int dj = 0; dj < 4; dj++)
                L.Os[row][dj * 16 + l16] = f2bf(oacc[mi][dj][r] * inv);
        }
    float rwf[33];
#pragma unroll
    for (int kk = 0; kk < 33; kk++) rwf[kk] = rw[h * 33 + kk];
#pragma unroll
    for (int half = 0; half < 2; half++) {
        const int rbase = w * 32 + half * 16;
        float vr[48];
#pragma unroll
        for (int s = 0; s < 48; s++) vr[s] = bf2f(Vs[rbase + s][lane]);
        float conv[16];
#pragma unroll
        for (int i = 0; i < 16; i++) conv[i] = 0.f;
#pragma unroll
        for (int kk = 0; kk < 33; kk++) {
            float wk = rwf[kk];
#pragma unroll
            for (int i = 0; i < 16; i++) conv[i] = fmaf(wk, vr[i + kk], conv[i]);
        }
        int t0 = m0 + rbase;
#pragma unroll
        for (int i = 0; i < 16; i++) {
            int tk = t0 + i;
            if (tk < NTOK) {
                float val = bf2f(L.Os[rbase + i][lane]) + conv[i];
                ohb[(long)tk * 512 + h * 64 + lane] = f2bf(val);
            }
        }
    }
}

// ---------------- layernorm over 512, writes bf16 xln (first `pad` rows zero)
__global__ __launch_bounds__(256)
void k_layernorm(const float* __restrict__ h, ushort* __restrict__ xln,
                 const float* __restrict__ g, const float* __restrict__ b, int pad)
{
    int row = blockIdx.x, t = threadIdx.x;
    if (row < pad) {
        xln[(long)row * 512 + t] = 0;
        xln[(long)row * 512 + t + 256] = 0;
        return;
    }
    const float* src = h + (long)(row - pad) * 512;
    float x1 = src[t], x2 = src[t + 256];
    float s = x1 + x2, q = x1 * x1 + x2 * x2;
    __shared__ float rs[4], rq[4], st[2];
    int wid = t >> 6, lane = t & 63;
#pragma unroll
    for (int o = 32; o > 0; o >>= 1) { s += __shfl_down(s, o); q += __shfl_down(q, o); }
    if (lane == 0) { rs[wid] = s; rq[wid] = q; }
    __syncthreads();
    if (t == 0) {
        float S = rs[0] + rs[1] + rs[2] + rs[3];
        float Q = rq[0] + rq[1] + rq[2] + rq[3];
        float mean = S / 512.f;
        float var = Q / 512.f - mean * mean;
        st[0] = mean; st[1] = rsqrtf(var + 1e-5f);
    }
    __syncthreads();
    float mean = st[0], rstd = st[1];
    xln[(long)row * 512 + t] = f2bf((x1 - mean) * rstd * g[t] + b[t]);
    xln[(long)row * 512 + t + 256] = f2bf((x2 - mean) * rstd * g[t + 256] + b[t + 256]);
}

__global__ __launch_bounds__(256)
void k_padcls(float* __restrict__ hbuf, const float* __restrict__ cls)
{
    int i = blockIdx.x, t = threadIdx.x;
    if (i == 0) { hbuf[t] = cls[t]; hbuf[t + 256] = cls[t + 256]; }
    else {
        hbuf[(long)(15000 + i) * 512 + t] = hbuf[(long)i * 512 + t];
        hbuf[(long)(15000 + i) * 512 + t + 256] = hbuf[(long)i * 512 + t + 256];
    }
}

__global__ __launch_bounds__(256)
void k_wT(const float* __restrict__ Wm, ushort* __restrict__ Wt, int K, int N, long sW, long sWt)
{
    Wm += (long)blockIdx.z * sW; Wt += (long)blockIdx.z * sWt;
    __shared__ float tile[32][33];
    int tx = threadIdx.x & 31, ty = threadIdx.x >> 5;
    int n0 = blockIdx.x * 32, k0 = blockIdx.y * 32;
#pragma unroll
    for (int u = 0; u < 4; u++) tile[ty + u * 8][tx] = Wm[(long)(k0 + ty + u * 8) * N + n0 + tx];
    __syncthreads();
#pragma unroll
    for (int u = 0; u < 4; u++) Wt[(long)(n0 + ty + u * 8) * K + k0 + tx] = f2bf(tile[tx][ty + u * 8]);
}

__global__ __launch_bounds__(64)
void k_landmarks(const ushort* __restrict__ q, const ushort* __restrict__ k,
                 float* __restrict__ ql, ushort* __restrict__ qlb,
                 float* __restrict__ klT, ushort* __restrict__ klb,
                 unsigned* __restrict__ scal)
{
    int i = blockIdx.x, h = blockIdx.y, d = threadIdx.x;
    if (i == 0 && h == 0 && d == 0) { scal[0] = 0u; scal[1] = 0u; }
    long base = ((long)h * NPQ + (long)i * 60) * 64 + d;
    float sq = 0.f, sk = 0.f;
    for (int j = 0; j < 60; j++) { sq += bf2f(q[base + j * 64]); sk += bf2f(k[base + j * 64]); }
    float qv = sq / 60.f, kv = sk / 60.f;
    ql[((long)h * 256 + i) * 64 + d] = qv;
    qlb[((long)h * 256 + i) * 64 + d] = f2bf(qv);
    klT[((long)h * 64 + d) * 256 + i] = kv;
    klb[((long)h * 256 + i) * 64 + d] = f2bf(kv);
}

__global__ __launch_bounds__(256)
void k_softmax256(float* __restrict__ X, ushort* __restrict__ X16, long headStride)
{
    float* row = X + (long)blockIdx.y * headStride + (long)blockIdx.x * 256;
    int t = threadIdx.x, wid = t >> 6, lane = t & 63;
    float x = row[t];
    __shared__ float rm[4], rsum[4], fin[2];
    float m = x;
#pragma unroll
    for (int o = 32; o > 0; o >>= 1) m = fmaxf(m, __shfl_down(m, o));
    if (lane == 0) rm[wid] = m;
    __syncthreads();
    if (t == 0) fin[0] = fmaxf(fmaxf(rm[0], rm[1]), fmaxf(rm[2], rm[3]));
    __syncthreads();
    float e = __expf(x - fin[0]);
    float s = e;
#pragma unroll
    for (int o = 32; o > 0; o >>= 1) s += __shfl_down(s, o);
    if (lane == 0) rsum[wid] = s;
    __syncthreads();
    if (t == 0) fin[1] = rsum[0] + rsum[1] + rsum[2] + rsum[3];
    __syncthreads();
    float v = e / fin[1];
    row[t] = v;
    if (X16) X16[(long)blockIdx.y * headStride + (long)blockIdx.x * 256 + t] = f2bf(v);
}

__global__ __launch_bounds__(256)
void k_colmax(const float* __restrict__ a2, unsigned* __restrict__ scal)
{
    int h = blockIdx.x, t = threadIdx.x, wid = t >> 6, lane = t & 63;
    const float* A = a2 + (long)h * 65536;
    float cs = 0.f, rs = 0.f;
    for (int i = 0; i < 256; i++) cs += A[(long)i * 256 + t];
    for (int j = 0; j < 256; j++) rs += A[(long)t * 256 + j];
    __shared__ float r1[4], r2[4];
    float m1v = cs, m2v = rs;
#pragma unroll
    for (int o = 32; o > 0; o >>= 1) {
        m1v = fmaxf(m1v, __shfl_down(m1v, o));
        m2v = fmaxf(m2v, __shfl_down(m2v, o));
    }
    if (lane == 0) { r1[wid] = m1v; r2[wid] = m2v; }
    __syncthreads();
    if (t == 0) {
        float a = fmaxf(fmaxf(r1[0], r1[1]), fmaxf(r1[2], r1[3]));
        float b = fmaxf(fmaxf(r2[0], r2[1]), fmaxf(r2[2], r2[3]));
        atomicMax(scal + 0, __float_as_uint(a));
        atomicMax(scal + 1, __float_as_uint(b));
    }
}

__global__ __launch_bounds__(256)
void k_zinit(const float* __restrict__ a2, ushort* __restrict__ zb, const unsigned* __restrict__ scal)
{
    float s = 1.f / (__uint_as_float(scal[0]) * __uint_as_float(scal[1]));
    const float* A = a2 + (long)blockIdx.z * 65536;
    ushort* Z = zb + (long)blockIdx.z * 65536;
    __shared__ float tile[32][33];
    int tx = threadIdx.x & 31, ty = threadIdx.x >> 5;
    int i0 = blockIdx.x * 32, j0 = blockIdx.y * 32;
#pragma unroll
    for (int u = 0; u < 4; u++) tile[ty + u * 8][tx] = A[(long)(j0 + ty + u * 8) * 256 + i0 + tx];
    __syncthreads();
#pragma unroll
    for (int u = 0; u < 4; u++) Z[(long)(i0 + ty + u * 8) * 256 + j0 + tx] = f2bf(tile[tx][ty + u * 8] * s);
}

__global__ __launch_bounds__(256)
void k_a3v_merge(const float* __restrict__ pacc, const float* __restrict__ pml,
                 float* __restrict__ t1)
{
    int d = blockIdx.x, h = blockIdx.y, i = threadIdx.x;
    float M = -INFINITY, L = 0.f, num = 0.f;
    for (int c = 0; c < 60; c++) {
        float mc = pml[(long)(h * 60 + c) * 2 * 256 + i];
        float lc = pml[((long)(h * 60 + c) * 2 + 1) * 256 + i];
        float ac = pacc[((long)(h * 60 + c) * 64 + d) * 256 + i];
        if (mc > M) {
            float f = __expf(M - mc);
            num = num * f + ac; L = L * f + lc; M = mc;
        } else {
            float p = __expf(mc - M);
            num = fmaf(p, ac, num); L = fmaf(p, lc, L);
        }
    }
    t1[((long)h * 256 + i) * 64 + d] = num / L;
}

__global__ __launch_bounds__(256)
void k_cls(const ushort* __restrict__ qb, const float* __restrict__ klT,
           const float* __restrict__ Bm, const ushort* __restrict__ vb,
           const float* __restrict__ rw, float* __restrict__ oh)
{
    int h = blockIdx.x, t = threadIdx.x, wid = t >> 6, lane = t & 63;
    __shared__ float qs[64], p[256], red[256];
    __shared__ float rm[4], rsum[4], fin[2];
    if (t < 64) qs[t] = bf2f(qb[((long)h * NPQ + 230) * 64 + t]);
    __syncthreads();
    float s = 0.f;
    for (int d = 0; d < 64; d++) s = fmaf(qs[d], klT[((long)h * 64 + d) * 256 + t], s);
    float m = s;
#pragma unroll
    for (int o = 32; o > 0; o >>= 1) m = fmaxf(m, __shfl_down(m, o));
    if (lane == 0) rm[wid] = m;
    __syncthreads();
    if (t == 0) fin[0] = fmaxf(fmaxf(rm[0], rm[1]), fmaxf(rm[2], rm[3]));
    __syncthreads();
    float e = __expf(s - fin[0]);
    float ss = e;
#pragma unroll
    for (int o = 32; o > 0; o >>= 1) ss += __shfl_down(ss, o);
    if (lane == 0) rsum[wid] = ss;
    __syncthreads();
    if (t == 0) fin[1] = rsum[0] + rsum[1] + rsum[2] + rsum[3];
    __syncthreads();
    p[t] = e / fin[1];
    __syncthreads();
    int d = t & 63, grp = t >> 6;
    float o = 0.f;
    for (int j = grp * 64; j < grp * 64 + 64; j++) o = fmaf(p[j], Bm[((long)h * 256 + j) * 64 + d], o);
    red[t] = o;
    __syncthreads();
    if (t < 64) {
        float val = red[t] + red[t + 64] + red[t + 128] + red[t + 192];
#pragma unroll
        for (int kk = 0; kk < 33; kk++)
            val = fmaf(rw[h * 33 + kk], bf2f(vb[((long)h * NPQ + 214 + kk) * 64 + t]), val);
        oh[h * 64 + t] = val;
    }
}

__global__ __launch_bounds__(256)
void k_copy4(const float4* __restrict__ src, float4* __restrict__ dst, long n4)
{
    long i = (long)blockIdx.x * 256 + threadIdx.x;
    if (i < n4) dst[i] = src[i];
}

// ---------------- combine w7+w5+w3+identity into wc[49][512], bc = b7+b5+b3
__global__ __launch_bounds__(512)
void k_wcomb(const float* __restrict__ w7, const float* __restrict__ b7,
             const float* __restrict__ w5, const float* __restrict__ b5,
             const float* __restrict__ w3, const float* __restrict__ b3,
             float* __restrict__ wc, float* __restrict__ bc)
{
    int k = blockIdx.x, c = threadIdx.x;
    int kr = k / 7, kc = k % 7;
    float v = w7[c * 49 + k];
    if (kr >= 1 && kr <= 5 && kc >= 1 && kc <= 5) v += w5[c * 25 + (kr - 1) * 5 + (kc - 1)];
    if (kr >= 2 && kr <= 4 && kc >= 2 && kc <= 4) v += w3[c * 9 + (kr - 2) * 3 + (kc - 2)];
    if (k == 24) v += 1.f;
    wc[k * 512 + c] = v;
    if (k == 0) bc[c] = b7[c] + b5[c] + b3[c];
}

// ---------------- PPEG v4: async DMA staging (global_load_lds w=16), (256,4).
__global__ __launch_bounds__(256, 4)
void k_ppeg4(const float* __restrict__ cnn, float* __restrict__ hbuf,
             const float* __restrict__ wc, const float* __restrict__ bc)
{
    __shared__ __attribute__((aligned(16))) float tile[320 * 32];
    const int t = threadIdx.x;
    const int w = t >> 6, lane = t & 63;
    const int c0 = blockIdx.x * 16;
    const int r0 = blockIdx.y * 8;
    const int cb = blockIdx.z * 32;
    {
        const int pl = lane >> 3;
        const int c4 = (lane & 7) * 4;
#pragma unroll
        for (int it = 0; it < 10; ++it) {
            int chunk = w * 10 + it;
            int pos = chunk * 8 + pl;
            int pr = pos / 22, pc = pos - pr * 22;
            int gr = r0 + pr - 3, gc = c0 + pc - 3;
            int grc = min(max(gr, 0), HG - 1), gcc = min(max(gc, 0), HG - 1);
            const float* src = cnn + (long)(grc * HG + gcc) * 512 + cb + c4;
            __builtin_amdgcn_global_load_lds(
                (const __attribute__((address_space(1))) void*)src,
                (__attribute__((address_space(3))) void*)(tile + chunk * 256),
                16, 0, 0);
        }
    }
    __syncthreads();
    const bool boundary = (r0 < 3) | (r0 > HG - 11) | (c0 < 3) | (c0 > HG - 19);
    if (boundary) {
        for (int pos = t; pos < 308; pos += 256) {
            int pr = pos / 22, pc = pos - pr * 22;
            int gr = r0 + pr - 3, gc = c0 + pc - 3;
            if (gr < 0 || gr >= HG || gc < 0 || gc >= HG) {
                float4 z = make_float4(0.f, 0.f, 0.f, 0.f);
#pragma unroll
                for (int c4 = 0; c4 < 32; c4 += 4) *(float4*)&tile[pos * 32 + c4] = z;
            }
        }
        __syncthreads();
    }
    const int cp = t & 15;
    const int slot = t >> 4;
    const int orow = slot >> 1;
    const int ohalf = (slot & 1) * 8;
    float a0[8], a1[8];
#pragma unroll
    for (int i = 0; i < 8; i++) { a0[i] = 0.f; a1[i] = 0.f; }
    for (int kr = 0; kr < 7; kr++) {
        float w0[14], w1[14];
        const float* trow = tile + ((orow + kr) * 22 + ohalf) * 32 + cp * 2;
#pragma unroll
        for (int j = 0; j < 14; j++) {
            float2 v = *(const float2*)(trow + j * 32);
            w0[j] = v.x; w1[j] = v.y;
        }
#pragma unroll
        for (int kc = 0; kc < 7; kc++) {
            float2 wv = *(const float2*)(wc + (long)(kr * 7 + kc) * 512 + cb + cp * 2);
#pragma unroll
            for (int i = 0; i < 8; i++) {
                a0[i] = fmaf(wv.x, w0[i + kc], a0[i]);
                a1[i] = fmaf(wv.y, w1[i + kc], a1[i]);
            }
        }
    }
    const float2 bv = *(const float2*)(bc + cb + cp * 2);
    const int gr = r0 + orow;
    if (gr < HG) {
#pragma unroll
        for (int i = 0; i < 8; i++) {
            int gc = c0 + ohalf + i;
            if (gc < HG) {
                float* dst = hbuf + (long)(1 + gr * HG + gc) * 512 + cb + cp * 2;
                dst[0] = a0[i] + bv.x;
                dst[1] = a1[i] + bv.y;
            }
        }
    }
}

__global__ __launch_bounds__(256)
void k_final(const float* __restrict__ hbuf, const float* __restrict__ g,
             const float* __restrict__ b, const float* __restrict__ W2,
             const float* __restrict__ b2, float* __restrict__ out)
{
    __shared__ float y[512];
    __shared__ float rs[4], rq[4], st[2], lg[8];
    int t = threadIdx.x, wid = t >> 6, lane = t & 63;
    float x1 = hbuf[t], x2 = hbuf[t + 256];
    float s = x1 + x2, q = x1 * x1 + x2 * x2;
#pragma unroll
    for (int o = 32; o > 0; o >>= 1) { s += __shfl_down(s, o); q += __shfl_down(q, o); }
    if (lane == 0) { rs[wid] = s; rq[wid] = q; }
    __syncthreads();
    if (t == 0) {
        float S = rs[0] + rs[1] + rs[2] + rs[3];
        float Q = rq[0] + rq[1] + rq[2] + rq[3];
        float mean = S / 512.f;
        float var = Q / 512.f - mean * mean;
        st[0] = mean; st[1] = rsqrtf(var + 1e-5f);
    }
    __syncthreads();
    float mean = st[0], rstd = st[1];
    y[t] = (x1 - mean) * rstd * g[t] + b[t];
    y[t + 256] = (x2 - mean) * rstd * g[t + 256] + b[t + 256];
    __syncthreads();
    if (t < 5) {
        float acc = b2[t];
        for (int kx = 0; kx < 512; kx++) acc = fmaf(y[kx], W2[kx * 5 + t], acc);
        lg[t] = acc;
    }
    __syncthreads();
    if (t == 0) {
        float mx = lg[0]; int am = 0;
        for (int j = 1; j < 5; j++) if (lg[j] > mx) { mx = lg[j]; am = j; }
        float e[5], se = 0.f;
        for (int j = 0; j < 5; j++) { e[j] = __expf(lg[j] - mx); se += e[j]; }
        for (int j = 0; j < 5; j++) { out[j] = lg[j]; out[5 + j] = e[j] / se; }
        out[10] = (float)am;
    }
}

extern "C" void kernel_launch(void* const* d_in, const int* in_sizes, int n_in,
                              void* d_out, int out_size, void* d_ws, size_t ws_size,
                              hipStream_t stream)
{
    const float* data  = (const float*)d_in[0];
    const float* Wfc1  = (const float*)d_in[1];
    const float* bfc1  = (const float*)d_in[2];
    const float* cls   = (const float*)d_in[3];
    const float* ln1g  = (const float*)d_in[4];
    const float* ln1b  = (const float*)d_in[5];
    const float* qkv1  = (const float*)d_in[6];
    const float* out1w = (const float*)d_in[7];
    const float* out1b = (const float*)d_in[8];
    const float* res1  = (const float*)d_in[9];
    const float* w7    = (const float*)d_in[10];
    const float* b7    = (const float*)d_in[11];
    const float* w5    = (const float*)d_in[12];
    const float* b5    = (const float*)d_in[13];
    const float* w3    = (const float*)d_in[14];
    const float* b3    = (const float*)d_in[15];
    const float* ln2g  = (const float*)d_in[16];
    const float* ln2b  = (const float*)d_in[17];
    const float* qkv2  = (const float*)d_in[18];
    const float* out2w = (const float*)d_in[19];
    const float* out2b = (const float*)d_in[20];
    const float* res2  = (const float*)d_in[21];
    const float* normg = (const float*)d_in[22];
    const float* normb = (const float*)d_in[23];
    const float* Wfc2  = (const float*)d_in[24];
    const float* bfc2  = (const float*)d_in[25];
    float* out = (float*)d_out;

    float* W = (float*)d_ws;
    size_t off = 0;
    auto alloc = [&](size_t n) { size_t o = off; off += (n + 255) & ~(size_t)255; return o; };
    float*  hbuf   = W + alloc((size_t)NTOK * 512);
    float*  ohreg  = W + alloc((size_t)15232 * 512);
    float*  oh     = ohreg;
    ushort* xln    = (ushort*)ohreg;
    ushort* qb16   = (ushort*)(W + alloc((size_t)8 * NPQ * 32));
    ushort* kb16   = (ushort*)(W + alloc((size_t)8 * NPQ * 32));
    ushort* vb16   = (ushort*)(W + alloc((size_t)8 * NPQ * 32));
    float*  ql     = W + alloc(8 * 256 * 64);
    ushort* qlb    = (ushort*)(W + alloc(8 * 256 * 32));
    float*  klT    = W + alloc(8 * 64 * 256);
    ushort* klb    = (ushort*)(W + alloc(8 * 256 * 32));
    float*  a2     = W + alloc(8 * 65536);
    ushort* a2b    = (ushort*)(W + alloc(8 * 32768));
    ushort* zb0    = (ushort*)(W + alloc(8 * 32768));
    ushort* zb1    = (ushort*)(W + alloc(8 * 32768));
    ushort* m1b    = (ushort*)(W + alloc(8 * 32768));
    ushort* mab    = (ushort*)(W + alloc(8 * 32768));
    ushort* mbb    = (ushort*)(W + alloc(8 * 32768));
    float*  z0     = W + alloc(8 * 65536);
    float*  t1     = W + alloc(8 * 256 * 64);
    float*  Bm     = W + alloc(8 * 256 * 64);
    ushort* BmbT   = (ushort*)(W + alloc(8 * 256 * 32));   // bf16 BmT [h][64][256]
    float*  scal   = W + alloc(64);
    ushort* ohb16  = (ushort*)(W + alloc((size_t)15232 * 256));
    ushort* WfcT   = (ushort*)(W + alloc(1024 * 256));
    ushort* qkv1T  = (ushort*)(W + alloc(1536 * 256));
    ushort* qkv2T  = (ushort*)(W + alloc(1536 * 256));
    ushort* out1T  = (ushort*)(W + alloc(512 * 256));
    ushort* out2T  = (ushort*)(W + alloc(512 * 256));
    float*  wc     = W + alloc(49 * 512);
    float*  bc     = W + alloc(512);
    float*  big    = W + alloc(8110080);   // pacc+pml | ppeg cnn
    float*  pacc   = big;
    float*  pml    = big + 7864320;
    float*  cnn    = big;
    (void)z0;
    if (ws_size < off * sizeof(float)) return;

    k_wT<<<dim3(16, 32, 1), 256, 0, stream>>>(Wfc1, WfcT, 1024, 512, 0, 0);
    k_wT<<<dim3(48, 16, 1), 256, 0, stream>>>(qkv1, qkv1T, 512, 1536, 0, 0);
    k_wT<<<dim3(48, 16, 1), 256, 0, stream>>>(qkv2, qkv2T, 512, 1536, 0, 0);
    k_wT<<<dim3(16, 16, 1), 256, 0, stream>>>(out1w, out1T, 512, 512, 0, 0);
    k_wT<<<dim3(16, 16, 1), 256, 0, stream>>>(out2w, out2T, 512, 512, 0, 0);
    k_wcomb<<<49, 512, 0, stream>>>(w7, b7, w5, b5, w3, b3, wc, bc);
    // fc1 GEMM with fused fp32->bf16 conversion, depth-2 STATIC prefetch
    gemm_fc1<<<dim3(4, 235, 1), 256, 0, stream>>>(data, WfcT, hbuf + 512, bfc1);
    k_padcls<<<130, 256, 0, stream>>>(hbuf, cls);

    auto layer = [&](const float* lng, const float* lnb, const ushort* qkvT,
                     const float* outW, const ushort* outT, const float* outB,
                     const float* resW, bool full) {
        k_layernorm<<<NP, 256, 0, stream>>>(hbuf, xln, lng, lnb, 230);
        gemm_qkv_mfma<<<dim3(12, 120, 1), 256, 0, stream>>>(xln, qkvT, qb16, kb16, vb16);
        k_landmarks<<<dim3(256, 8), 64, 0, stream>>>(qb16, kb16, ql, qlb, klT, klb, (unsigned*)scal);
        gemm_f32<<<dim3(4, 4, 8), 256, 0, stream>>>(ql, 64, 16384, klT, 256, 16384,
            a2, 256, 65536, 256, 256, 64, nullptr, nullptr, 0, 0, 0.f, 1.f, 0, 0);
        k_softmax256<<<dim3(256, 8), 256, 0, stream>>>(a2, a2b, 65536);
        k_colmax<<<8, 256, 0, stream>>>(a2, (unsigned*)scal);
        k_zinit<<<dim3(8, 8, 8), 256, 0, stream>>>(a2, zb0, (const unsigned*)scal);
        // pinv: all 6 iterations bf16 MFMA (prefetch + swizzled B^T staging)
        ushort* zbi = zb0; ushort* zbo = zb1;
        for (int it = 0; it < 6; ++it) {
            gemm_nn16<<<dim3(4, 4, 8), 256, 0, stream>>>(a2b, zbi, nullptr, m1b, 256, 256, 1.f, 0.f, 65536);
            gemm_nn16<<<dim3(4, 4, 8), 256, 0, stream>>>(m1b, m1b, m1b, mab, 256, 256, -1.f, 7.f, 65536);
            gemm_nn16<<<dim3(4, 4, 8), 256, 0, stream>>>(m1b, mab, m1b, mbb, 256, 256, -1.f, 15.f, 65536);
            gemm_nn16<<<dim3(4, 4, 8), 256, 0, stream>>>(zbi, mbb, zbi, zbo, 256, 256, -0.25f, 3.25f, 65536);
            ushort* tmp = zbi; zbi = zbo; zbo = tmp;
        }
        k_flash_a3v<<<dim3(60, 2, 8), 256, 0, stream>>>(qlb, kb16, vb16, pacc, pml);
        k_a3v_merge<<<dim3(64, 8), 256, 0, stream>>>(pacc, pml, t1);
        // Bm = z(bf16) @ t1 directly
        gemm_zb<<<dim3(1, 4, 8), 256, 0, stream>>>(zbi, t1, Bm);
        if (full) {
            k_wT<<<dim3(2, 8, 8), 256, 0, stream>>>(Bm, BmbT, 256, 64, 16384, 16384);
            k_attn1<<<dim3(119, 8), 256, 0, stream>>>(qb16, klb, BmbT, vb16, resW, ohb16);
            gemm_mfma<2, 4, 2, 2><<<dim3(4, 237, 1), 256, 0, stream>>>(
                ohb16, 512, 0, outT, 512, 0, hbuf, 512, 0, NTOK, 512, outB, 0, 1);
        } else {
            k_cls<<<8, 256, 0, stream>>>(qb16, klT, Bm, vb16, resW, oh);
            gemm_f32<<<dim3(8, 1, 1), 256, 0, stream>>>(oh, 512, 0, outW, 512, 0,
                hbuf, 512, 0, 1, 512, 512, outB, nullptr, 0, 0, 0.f, 1.f, 0, 1);
        }
    };

    layer(ln1g, ln1b, qkv1T, out1w, out1T, out1b, res1, true);
    k_copy4<<<(1936512 + 255) / 256, 256, 0, stream>>>((const float4*)(hbuf + 512), (float4*)cnn, 1936512);
    k_ppeg4<<<dim3(8, 16, 16), 256, 0, stream>>>(cnn, hbuf, wc, bc);
    layer(ln2g, ln2b, qkv2T, out2w, out2T, out2b, res2, false);
    k_final<<<1, 256, 0, stream>>>(hbuf, normg, normb, Wfc2, bfc2, out);
}